// Round 1
// baseline (888.518 us; speedup 1.0000x reference)
//
#include <hip/hip_runtime.h>
#include <math.h>

#define BATCH 128
#define NPRI  32768
#define NOBJ  20
#define THRSH 0.5f
#define VARNC 0.1f

// ---- workspace layout (needs ~21 MB) ----
// [0,24)            double acc[3]  : loss_l, loss_c, loss_r
// [64, 64+512)      int npos[BATCH]
// [1024, +20480)    ull  bpk[BATCH*NOBJ]   packed (iou_bits<<32)|(~prior_idx)
// [32768, +16MB)    float lcpp[BATCH*NPRI]
// [32768+16MB, +4MB) uchar conf[BATCH*NPRI]
#define OFF_ACC  0
#define OFF_NPOS 64
#define OFF_BPK  1024
#define OFF_LCPP 32768
#define OFF_CONF (32768 + 4 * BATCH * NPRI)

__device__ __forceinline__ float sl1(float d) {
    d = fabsf(d);
    return (d < 1.0f) ? 0.5f * d * d : d - 0.5f;
}

__device__ __forceinline__ float bce1(float x, bool hot) {
    float tgt = hot ? 0.925f : 0.025f;   // one_hot*(1-0.1) + 0.1/4
    return fmaxf(x, 0.0f) - x * tgt + log1pf(expf(-fabsf(x)));
}

// ---------------- kernel A: per-truth argmax over priors ----------------
__global__ __launch_bounds__(256) void kA(const float* __restrict__ targets,
                                          const float4* __restrict__ priors,
                                          unsigned long long* __restrict__ bpk) {
    const int b = blockIdx.y;
    const int p = blockIdx.x * 256 + threadIdx.x;
    __shared__ float st[NOBJ * 6];
    __shared__ unsigned long long skey[NOBJ];
    if (threadIdx.x < NOBJ * 6) st[threadIdx.x] = targets[b * NOBJ * 6 + threadIdx.x];
    if (threadIdx.x < NOBJ) skey[threadIdx.x] = 0ull;
    __syncthreads();

    const float4 pr = priors[p];
    const float px0 = pr.x - pr.z * 0.5f, py0 = pr.y - pr.w * 0.5f;
    const float px1 = pr.x + pr.z * 0.5f, py1 = pr.y + pr.w * 0.5f;
    const float areab = (px1 - px0) * (py1 - py0);
    const int lane = threadIdx.x & 63, w = threadIdx.x >> 6;

    for (int o = 0; o < NOBJ; ++o) {
        const float t0 = st[o * 6], t1 = st[o * 6 + 1], t2 = st[o * 6 + 2], t3 = st[o * 6 + 3];
        float ix = fminf(t2, px1) - fmaxf(t0, px0); ix = fmaxf(ix, 0.0f);
        float iy = fminf(t3, py1) - fmaxf(t1, py0); iy = fmaxf(iy, 0.0f);
        const float inter = ix * iy;
        const float areaa = (t2 - t0) * (t3 - t1);
        const float iou = inter / (areaa + areab - inter);
        // wave-wide max (all values >= 0, no NaN)
        float m = iou;
        #pragma unroll
        for (int s = 32; s > 0; s >>= 1) m = fmaxf(m, __shfl_xor(m, s, 64));
        const unsigned long long msk = __ballot(iou == m);
        if (lane == 0) {
            const int src = __builtin_ctzll(msk);            // lowest lane = lowest prior idx
            const unsigned wp = (unsigned)(blockIdx.x * 256 + w * 64 + src);
            const unsigned long long key =
                ((unsigned long long)__float_as_uint(m) << 32) |
                (unsigned long long)(0xFFFFFFFFu - wp);       // max key -> max iou, tie -> min idx
            atomicMax(&skey[o], key);
        }
    }
    __syncthreads();
    if (threadIdx.x < NOBJ) atomicMax(&bpk[b * NOBJ + threadIdx.x], skey[threadIdx.x]);
}

// ---------------- kernel B: match + loc/reg losses + loss_cpp ----------------
__global__ __launch_bounds__(256) void kB(const float* __restrict__ targets,
                                          const float4* __restrict__ priors,
                                          const float2* __restrict__ loc,
                                          const float4* __restrict__ cnf,
                                          const float* __restrict__ reg,
                                          const unsigned long long* __restrict__ bpk,
                                          float* __restrict__ lcpp,
                                          unsigned char* __restrict__ confb,
                                          double* __restrict__ acc,
                                          int* __restrict__ npos) {
    const int b = blockIdx.y;
    const int p = blockIdx.x * 256 + threadIdx.x;
    __shared__ float st[NOBJ * 6];
    __shared__ int sbpi[NOBJ];
    __shared__ float sred[4][2];
    __shared__ int sredn[4];
    if (threadIdx.x < NOBJ * 6) st[threadIdx.x] = targets[b * NOBJ * 6 + threadIdx.x];
    if (threadIdx.x < NOBJ) {
        unsigned low = (unsigned)(bpk[b * NOBJ + threadIdx.x] & 0xFFFFFFFFull);
        sbpi[threadIdx.x] = (int)(0xFFFFFFFFu - low);   // 0 init -> -1 -> matches nothing
    }
    __syncthreads();

    const float4 pr = priors[p];
    const float px0 = pr.x - pr.z * 0.5f, py0 = pr.y - pr.w * 0.5f;
    const float px1 = pr.x + pr.z * 0.5f, py1 = pr.y + pr.w * 0.5f;
    const float areab = (px1 - px0) * (py1 - py0);

    float bto = -1.0f; int bti = 0;
    for (int o = 0; o < NOBJ; ++o) {     // strict > : first-occurrence argmax (matches jnp)
        const float t0 = st[o * 6], t1 = st[o * 6 + 1], t2 = st[o * 6 + 2], t3 = st[o * 6 + 3];
        float ix = fminf(t2, px1) - fmaxf(t0, px0); ix = fmaxf(ix, 0.0f);
        float iy = fminf(t3, py1) - fmaxf(t1, py0); iy = fmaxf(iy, 0.0f);
        const float inter = ix * iy;
        const float areaa = (t2 - t0) * (t3 - t1);
        const float iou = inter / (areaa + areab - inter);
        if (iou > bto) { bto = iou; bti = o; }
    }
    #pragma unroll 1
    for (int o = 0; o < NOBJ; ++o)       // serial scatter override, last o wins (CPU-scatter order)
        if (sbpi[o] == p) { bto = 2.0f; bti = o; }

    int c = 0;
    if (bto >= THRSH) c = (int)st[bti * 6 + 4];
    const bool pos = c > 0;

    const float4 x = cnf[(size_t)b * NPRI + p];
    const float m = fmaxf(fmaxf(x.x, x.y), fmaxf(x.z, x.w));
    const float lse = m + logf(expf(x.x - m) + expf(x.y - m) + expf(x.z - m) + expf(x.w - m));
    const float picked = (c == 0) ? x.x : (c == 1) ? x.y : (c == 2) ? x.z : x.w;
    lcpp[(size_t)b * NPRI + p] = pos ? 0.0f : (lse - picked);
    confb[(size_t)b * NPRI + p] = (unsigned char)c;

    float ll = 0.0f, lr = 0.0f; int np = 0;
    if (pos) {
        const float* t = &st[bti * 6];
        const float cx = (t[0] + t[2]) * 0.5f, cy = (t[1] + t[3]) * 0.5f;
        const float lt0 = (cx - pr.x) / (VARNC * pr.z);
        const float lt1 = (cy - pr.y) / (VARNC * pr.w);
        const float2 ld = loc[(size_t)b * NPRI + p];
        ll = sl1(ld.x - lt0) + sl1(ld.y - lt1);
        lr = sl1(reg[(size_t)b * NPRI + p] - t[5]);
        np = 1;
    }
    #pragma unroll
    for (int s = 32; s > 0; s >>= 1) {
        ll += __shfl_down(ll, s, 64);
        lr += __shfl_down(lr, s, 64);
        np += __shfl_down(np, s, 64);
    }
    const int lane = threadIdx.x & 63, w = threadIdx.x >> 6;
    if (lane == 0) { sred[w][0] = ll; sred[w][1] = lr; sredn[w] = np; }
    __syncthreads();
    if (threadIdx.x == 0) {
        const float tl = sred[0][0] + sred[1][0] + sred[2][0] + sred[3][0];
        const float tr = sred[0][1] + sred[1][1] + sred[2][1] + sred[3][1];
        const int tn = sredn[0] + sredn[1] + sredn[2] + sredn[3];
        if (tn) {
            atomicAdd(&acc[0], (double)tl);
            atomicAdd(&acc[2], (double)tr);
            atomicAdd(&npos[b], tn);
        }
    }
}

// ---------------- kernel C: radix-select top-k + BCE over selected ----------------
__global__ __launch_bounds__(256) void kC(const float* __restrict__ lcpp,
                                          const unsigned char* __restrict__ confb,
                                          const float4* __restrict__ cnf,
                                          const int* __restrict__ npos,
                                          double* __restrict__ acc) {
    const int b = blockIdx.x;
    const int tid = threadIdx.x;
    const float* v = lcpp + (size_t)b * NPRI;
    __shared__ unsigned int h[256];
    __shared__ unsigned int sPrefix;
    __shared__ unsigned int sT;
    __shared__ int sRem;

    const int k = min(3 * npos[b], NPRI - 1);
    if (tid == 0) sPrefix = 0;

    if (k <= 0) {
        if (tid == 0) { sT = 0xFFFFFFFFu; sRem = 0; }
        __syncthreads();
    } else {
        // loss_cpp >= 0 -> uint bit order == float order. Find value of rank k-1 (descending).
        unsigned int prefix = 0; int r = k - 1; unsigned int gt = 0;   // live on tid 0
        for (int pass = 0; pass < 4; ++pass) {
            const int shift = 24 - 8 * pass;
            h[tid] = 0;
            __syncthreads();
            const unsigned int pfx = sPrefix;
            const unsigned int hi_mask = (pass == 0) ? 0u : (0xFFFFFFFFu << (shift + 8));
            for (int i = tid; i < NPRI; i += 256) {
                const unsigned int u = __float_as_uint(v[i]);
                if ((u & hi_mask) == pfx) atomicAdd(&h[(u >> shift) & 255], 1u);
            }
            __syncthreads();
            if (tid == 0) {
                for (int bin = 255; bin >= 0; --bin) {
                    const int cbin = (int)h[bin];
                    if (r < cbin) { prefix |= ((unsigned)bin) << shift; sPrefix = prefix; break; }
                    r -= cbin; gt += (unsigned)cbin;
                }
            }
            __syncthreads();
        }
        if (tid == 0) { sT = prefix; sRem = r + 1; }   // rem = k - cnt_gt = ties to accept
        __syncthreads();
    }
    const unsigned int T = sT;
    const int rem = sRem;

    // final pass in index order: stable tie-ranking + BCE on selected
    float localc = 0.0f;
    __shared__ int s_runtie;
    __shared__ int s_wcnt[4];
    if (tid == 0) s_runtie = 0;
    __syncthreads();
    const int lane = tid & 63, w = tid >> 6;
    for (int chunk = 0; chunk < NPRI / 256; ++chunk) {
        const int i = chunk * 256 + tid;
        const unsigned int u = __float_as_uint(v[i]);
        const bool tie = (u == T);
        const unsigned long long msk = __ballot(tie);
        if (lane == 0) s_wcnt[w] = __popcll(msk);
        __syncthreads();
        int off = 0;
        #pragma unroll
        for (int j = 0; j < 4; ++j) if (j < w) off += s_wcnt[j];
        const int ctot = s_wcnt[0] + s_wcnt[1] + s_wcnt[2] + s_wcnt[3];
        const int myrank = s_runtie + off + __popcll(msk & ((1ull << lane) - 1ull));
        const unsigned char c = confb[(size_t)b * NPRI + i];
        const bool sel = (c > 0) || (u > T) || (tie && myrank < rem);
        if (sel) {
            const float4 x = cnf[(size_t)b * NPRI + i];
            localc += bce1(x.x, c == 0) + bce1(x.y, c == 1) + bce1(x.z, c == 2) + bce1(x.w, c == 3);
        }
        __syncthreads();
        if (tid == 0) s_runtie += ctot;
    }
    #pragma unroll
    for (int s = 32; s > 0; s >>= 1) localc += __shfl_down(localc, s, 64);
    __shared__ float sc[4];
    if (lane == 0) sc[w] = localc;
    __syncthreads();
    if (tid == 0) atomicAdd(&acc[1], (double)(sc[0] + sc[1] + sc[2] + sc[3]));
}

// ---------------- kernel D: finalize ----------------
__global__ void kD(const double* __restrict__ acc, const int* __restrict__ npos,
                   float* __restrict__ out) {
    if (threadIdx.x == 0 && blockIdx.x == 0) {
        int n = 0;
        for (int b = 0; b < BATCH; ++b) n += npos[b];
        const double N = (double)n;
        out[0] = (float)(acc[0] / N);
        out[1] = (float)(acc[1] / N);
        out[2] = (float)(acc[2] / N);
    }
}

extern "C" void kernel_launch(void* const* d_in, const int* in_sizes, int n_in,
                              void* d_out, int out_size, void* d_ws, size_t ws_size,
                              hipStream_t stream) {
    const float* loc = (const float*)d_in[0];
    const float* cnfp = (const float*)d_in[1];
    const float* regp = (const float*)d_in[2];
    const float* tgt = (const float*)d_in[3];
    const float* pri = (const float*)d_in[4];

    char* ws = (char*)d_ws;
    double* acc = (double*)(ws + OFF_ACC);
    int* npos = (int*)(ws + OFF_NPOS);
    unsigned long long* bpk = (unsigned long long*)(ws + OFF_BPK);
    float* lcpp = (float*)(ws + OFF_LCPP);
    unsigned char* confb = (unsigned char*)(ws + OFF_CONF);

    hipMemsetAsync(ws, 0, 32768, stream);   // zero acc/npos/bpk header

    dim3 grid(NPRI / 256, BATCH);
    kA<<<grid, 256, 0, stream>>>(tgt, (const float4*)pri, bpk);
    kB<<<grid, 256, 0, stream>>>(tgt, (const float4*)pri, (const float2*)loc,
                                 (const float4*)cnfp, regp, bpk, lcpp, confb, acc, npos);
    kC<<<BATCH, 256, 0, stream>>>(lcpp, confb, (const float4*)cnfp, npos, acc);
    kD<<<1, 64, 0, stream>>>(acc, npos, (float*)d_out);
}

// Round 2
// 553.866 us; speedup vs baseline: 1.6042x; 1.6042x over previous
//
#include <hip/hip_runtime.h>
#include <math.h>

#define BATCH 128
#define NPRI  32768
#define NOBJ  20
#define THRSH 0.5f
#define VARNC 0.1f

// ---- workspace layout (~28.8 MB) ----
#define OFF_ACC  0                      // 3 doubles
#define OFF_NPOS 64                     // 128 ints
#define OFF_BPK  1024                   // 2560 ull
#define OFF_SEL  21504                  // uint sel[768]: [0]P1 [128]R [256]P2 [384]T [512]REM [640]EQ
#define OFF_H2   24576                  // 128*256 uint
#define OFF_H3   155648                 // 128*256 uint
#define OFF_LCPP (1 << 19)              // 16 MB float
#define OFF_CONF (OFF_LCPP + 4 * BATCH * NPRI)   // 4 MB bytes
#define OFF_H1   (OFF_CONF + BATCH * NPRI)       // 8 MB: 16384 words/batch, 2 bins/word
#define H1_BYTES (BATCH * 16384 * 4)

__device__ __forceinline__ float sl1(float d) {
    d = fabsf(d);
    return (d < 1.0f) ? 0.5f * d * d : d - 0.5f;
}
__device__ __forceinline__ float bce1(float x, bool hot) {
    float tgt = hot ? 0.925f : 0.025f;
    return fmaxf(x, 0.0f) - x * tgt + log1pf(expf(-fabsf(x)));
}

// ---------------- kA: per-truth best prior (16 priors/thread) ----------------
__global__ __launch_bounds__(256) void kA(const float* __restrict__ targets,
                                          const float4* __restrict__ priors,
                                          unsigned long long* __restrict__ bpk) {
    const int b = blockIdx.y;
    const int tid = threadIdx.x;
    float t0[NOBJ], t1[NOBJ], t2[NOBJ], t3[NOBJ], aa[NOBJ];
    #pragma unroll
    for (int o = 0; o < NOBJ; ++o) {
        const float* t = targets + (b * NOBJ + o) * 6;
        t0[o] = t[0]; t1[o] = t[1]; t2[o] = t[2]; t3[o] = t[3];
        aa[o] = (t2[o] - t0[o]) * (t3[o] - t1[o]);
    }
    float best[NOBJ]; int bp[NOBJ];
    #pragma unroll
    for (int o = 0; o < NOBJ; ++o) { best[o] = -1.0f; bp[o] = 0; }

    for (int it = 0; it < 16; ++it) {
        const int p = blockIdx.x * 4096 + it * 256 + tid;
        const float4 pr = priors[p];
        const float px0 = pr.x - pr.z * 0.5f, py0 = pr.y - pr.w * 0.5f;
        const float px1 = pr.x + pr.z * 0.5f, py1 = pr.y + pr.w * 0.5f;
        const float areab = (px1 - px0) * (py1 - py0);
        #pragma unroll
        for (int o = 0; o < NOBJ; ++o) {
            float ix = fminf(t2[o], px1) - fmaxf(t0[o], px0); ix = fmaxf(ix, 0.0f);
            float iy = fminf(t3[o], py1) - fmaxf(t1[o], py0); iy = fmaxf(iy, 0.0f);
            const float inter = ix * iy;
            const float iou = inter / (aa[o] + areab - inter);
            if (iou > best[o]) { best[o] = iou; bp[o] = p; }   // ascending p: first max = min idx
        }
    }
    __shared__ unsigned long long skey[NOBJ];
    if (tid < NOBJ) skey[tid] = 0ull;
    __syncthreads();
    const int lane = tid & 63;
    #pragma unroll
    for (int o = 0; o < NOBJ; ++o) {
        unsigned long long key = ((unsigned long long)__float_as_uint(best[o]) << 32)
                               | (unsigned long long)(0xFFFFFFFFu - (unsigned)bp[o]);
        #pragma unroll
        for (int s = 32; s > 0; s >>= 1) {
            unsigned long long k2 = __shfl_xor(key, s, 64);
            if (k2 > key) key = k2;
        }
        if (lane == 0) atomicMax(&skey[o], key);
    }
    __syncthreads();
    if (tid < NOBJ) atomicMax(&bpk[b * NOBJ + tid], skey[tid]);
}

// ---------------- kB: match + loc/reg losses + loss_cpp + level-1 hist ----------------
__global__ __launch_bounds__(256) void kB(const float* __restrict__ targets,
                                          const float4* __restrict__ priors,
                                          const float2* __restrict__ loc,
                                          const float4* __restrict__ cnf,
                                          const float* __restrict__ reg,
                                          const unsigned long long* __restrict__ bpk,
                                          float* __restrict__ lcpp,
                                          unsigned char* __restrict__ confb,
                                          unsigned int* __restrict__ hist1,
                                          double* __restrict__ acc,
                                          int* __restrict__ npos) {
    const int b = blockIdx.y;
    const int p = blockIdx.x * 256 + threadIdx.x;
    __shared__ float st[NOBJ * 6];
    __shared__ int sbpi[NOBJ];
    __shared__ float sred[4][2];
    __shared__ int sredn[4];
    if (threadIdx.x < NOBJ * 6) st[threadIdx.x] = targets[b * NOBJ * 6 + threadIdx.x];
    if (threadIdx.x < NOBJ) {
        unsigned low = (unsigned)(bpk[b * NOBJ + threadIdx.x] & 0xFFFFFFFFull);
        sbpi[threadIdx.x] = (int)(0xFFFFFFFFu - low);
    }
    __syncthreads();

    const float4 pr = priors[p];
    const float px0 = pr.x - pr.z * 0.5f, py0 = pr.y - pr.w * 0.5f;
    const float px1 = pr.x + pr.z * 0.5f, py1 = pr.y + pr.w * 0.5f;
    const float areab = (px1 - px0) * (py1 - py0);

    float bto = -1.0f; int bti = 0;
    for (int o = 0; o < NOBJ; ++o) {
        const float t0 = st[o * 6], t1 = st[o * 6 + 1], t2 = st[o * 6 + 2], t3 = st[o * 6 + 3];
        float ix = fminf(t2, px1) - fmaxf(t0, px0); ix = fmaxf(ix, 0.0f);
        float iy = fminf(t3, py1) - fmaxf(t1, py0); iy = fmaxf(iy, 0.0f);
        const float inter = ix * iy;
        const float areaa = (t2 - t0) * (t3 - t1);
        const float iou = inter / (areaa + areab - inter);
        if (iou > bto) { bto = iou; bti = o; }
    }
    #pragma unroll 1
    for (int o = 0; o < NOBJ; ++o)
        if (sbpi[o] == p) { bto = 2.0f; bti = o; }

    int c = 0;
    if (bto >= THRSH) c = (int)st[bti * 6 + 4];
    const bool pos = c > 0;

    const float4 x = cnf[(size_t)b * NPRI + p];
    const float m = fmaxf(fmaxf(x.x, x.y), fmaxf(x.z, x.w));
    const float lse = m + logf(expf(x.x - m) + expf(x.y - m) + expf(x.z - m) + expf(x.w - m));
    const float picked = (c == 0) ? x.x : (c == 1) ? x.y : (c == 2) ? x.z : x.w;
    const float lval = pos ? 0.0f : (lse - picked);
    lcpp[(size_t)b * NPRI + p] = lval;
    confb[(size_t)b * NPRI + p] = (unsigned char)c;
    const unsigned int u = __float_as_uint(lval);            // >= 0 -> 15-bit bin
    atomicAdd(&hist1[b * 16384 + (u >> 17)], 1u << (16 * ((u >> 16) & 1u)));

    float ll = 0.0f, lr = 0.0f; int np = 0;
    if (pos) {
        const float* t = &st[bti * 6];
        const float cx = (t[0] + t[2]) * 0.5f, cy = (t[1] + t[3]) * 0.5f;
        const float lt0 = (cx - pr.x) / (VARNC * pr.z);
        const float lt1 = (cy - pr.y) / (VARNC * pr.w);
        const float2 ld = loc[(size_t)b * NPRI + p];
        ll = sl1(ld.x - lt0) + sl1(ld.y - lt1);
        lr = sl1(reg[(size_t)b * NPRI + p] - t[5]);
        np = 1;
    }
    #pragma unroll
    for (int s = 32; s > 0; s >>= 1) {
        ll += __shfl_down(ll, s, 64);
        lr += __shfl_down(lr, s, 64);
        np += __shfl_down(np, s, 64);
    }
    const int lane = threadIdx.x & 63, w = threadIdx.x >> 6;
    if (lane == 0) { sred[w][0] = ll; sred[w][1] = lr; sredn[w] = np; }
    __syncthreads();
    if (threadIdx.x == 0) {
        const float tl = sred[0][0] + sred[1][0] + sred[2][0] + sred[3][0];
        const float tr = sred[0][1] + sred[1][1] + sred[2][1] + sred[3][1];
        const int tn = sredn[0] + sredn[1] + sredn[2] + sredn[3];
        if (tn) {
            atomicAdd(&acc[0], (double)tl);
            atomicAdd(&acc[2], (double)tr);
            atomicAdd(&npos[b], tn);
        }
    }
}

// ---------------- S1: scan level-1 hist, find 15-bit bin ----------------
__global__ __launch_bounds__(256) void kS1(const unsigned int* __restrict__ hist1,
                                           const int* __restrict__ npos,
                                           unsigned int* __restrict__ hist2,
                                           unsigned int* __restrict__ sel) {
    const int b = blockIdx.x, tid = threadIdx.x;
    hist2[b * 256 + tid] = 0;
    __shared__ unsigned int H[16384];
    __shared__ unsigned int part[256];
    const unsigned int* src = hist1 + b * 16384;
    for (int w = tid; w < 16384; w += 256) H[w] = src[w];
    __syncthreads();
    const int k = min(3 * npos[b], NPRI - 1);
    if (k <= 0) {
        if (tid == 0) { sel[b] = 0xFFFFFFFFu; sel[384 + b] = 0xFFFFFFFFu; sel[512 + b] = 0; sel[640 + b] = 0; }
        return;
    }
    unsigned int s = 0;
    for (int w = tid * 64; w < tid * 64 + 64; ++w) { unsigned int x = H[w]; s += (x & 0xFFFFu) + (x >> 16); }
    part[tid] = s;
    __syncthreads();
    if (tid == 0) {
        int r = k - 1; int t2 = 255;
        for (; t2 > 0; --t2) { if (r < (int)part[t2]) break; r -= (int)part[t2]; }
        int b1 = t2 * 128;
        for (int bin = t2 * 128 + 127; bin >= t2 * 128; --bin) {
            const int c = (int)((H[bin >> 1] >> (16 * (bin & 1))) & 0xFFFFu);
            if (r < c) { b1 = bin; break; }
            r -= c;
        }
        sel[b] = (unsigned)b1; sel[128 + b] = (unsigned)r;
    }
}

// ---------------- H2: hist of bits[15:8] among level-1-bin candidates ----------------
__global__ __launch_bounds__(256) void kH2(const float* __restrict__ lcpp,
                                           const unsigned int* __restrict__ sel,
                                           unsigned int* __restrict__ hist2) {
    const int b = blockIdx.y;
    const unsigned int b1 = sel[b];
    const float* v = lcpp + (size_t)b * NPRI;
    const int base = blockIdx.x * 4096 + threadIdx.x;
    for (int it = 0; it < 16; ++it) {
        const unsigned int u = __float_as_uint(v[base + it * 256]);
        if ((u >> 16) == b1) atomicAdd(&hist2[b * 256 + ((u >> 8) & 255u)], 1u);
    }
}

// ---------------- S2 ----------------
__global__ __launch_bounds__(256) void kS2(const unsigned int* __restrict__ hist2,
                                           unsigned int* __restrict__ hist3,
                                           unsigned int* __restrict__ sel) {
    const int b = blockIdx.x, tid = threadIdx.x;
    hist3[b * 256 + tid] = 0;
    __shared__ unsigned int sh[256];
    sh[tid] = hist2[b * 256 + tid];
    __syncthreads();
    if (tid == 0) {
        const unsigned int p1 = sel[b];
        if (p1 == 0xFFFFFFFFu) { sel[256 + b] = 0xFFFFFFFFu; return; }
        int r = (int)sel[128 + b];
        int b2 = 0;
        for (int bin = 255; bin >= 0; --bin) { const int c = (int)sh[bin]; if (r < c) { b2 = bin; break; } r -= c; }
        sel[256 + b] = (p1 << 8) | (unsigned)b2; sel[128 + b] = (unsigned)r;
    }
}

// ---------------- H3: hist of bits[7:0] among 24-bit-prefix candidates ----------------
__global__ __launch_bounds__(256) void kH3(const float* __restrict__ lcpp,
                                           const unsigned int* __restrict__ sel,
                                           unsigned int* __restrict__ hist3) {
    const int b = blockIdx.y;
    const unsigned int p2 = sel[256 + b];
    const float* v = lcpp + (size_t)b * NPRI;
    const int base = blockIdx.x * 4096 + threadIdx.x;
    for (int it = 0; it < 16; ++it) {
        const unsigned int u = __float_as_uint(v[base + it * 256]);
        if ((u >> 8) == p2) atomicAdd(&hist3[b * 256 + (u & 255u)], 1u);
    }
}

// ---------------- S3: exact threshold + tie counts ----------------
__global__ __launch_bounds__(256) void kS3(const unsigned int* __restrict__ hist3,
                                           unsigned int* __restrict__ sel) {
    const int b = blockIdx.x, tid = threadIdx.x;
    __shared__ unsigned int sh[256];
    sh[tid] = hist3[b * 256 + tid];
    __syncthreads();
    if (tid == 0) {
        const unsigned int p2 = sel[256 + b];
        if (p2 == 0xFFFFFFFFu) return;          // T/REM/EQ already set by S1
        int r = (int)sel[128 + b];
        int b3 = 0;
        for (int bin = 255; bin >= 0; --bin) { const int c = (int)sh[bin]; if (r < c) { b3 = bin; break; } r -= c; }
        sel[384 + b] = (p2 << 8) | (unsigned)b3;
        sel[512 + b] = (unsigned)(r + 1);
        sel[640 + b] = sh[b3];
    }
}

// ---------------- kTie: demote excess ties (rare path; stable by index) ----------------
__global__ __launch_bounds__(256) void kTie(float* __restrict__ lcpp,
                                            const unsigned int* __restrict__ sel) {
    const int b = blockIdx.x, tid = threadIdx.x;
    const unsigned int T = sel[384 + b];
    const int rem = (int)sel[512 + b];
    const int eq = (int)sel[640 + b];
    if (eq <= rem || T == 0u) return;
    float* v = lcpp + (size_t)b * NPRI;
    __shared__ int s_run;
    __shared__ int s_wcnt[4];
    if (tid == 0) s_run = 0;
    __syncthreads();
    const int lane = tid & 63, w = tid >> 6;
    for (int chunk = 0; chunk < NPRI / 256; ++chunk) {
        const int i = chunk * 256 + tid;
        const unsigned int u = __float_as_uint(v[i]);
        const bool tie = (u == T);
        const unsigned long long msk = __ballot(tie);
        if (lane == 0) s_wcnt[w] = __popcll(msk);
        __syncthreads();
        int off = 0;
        #pragma unroll
        for (int j = 0; j < 4; ++j) if (j < w) off += s_wcnt[j];
        const int ctot = s_wcnt[0] + s_wcnt[1] + s_wcnt[2] + s_wcnt[3];
        const int myrank = s_run + off + __popcll(msk & ((1ull << lane) - 1ull));
        if (tie && myrank >= rem) v[i] = __uint_as_float(T - 1u);
        __syncthreads();
        if (tid == 0) s_run += ctot;
        __syncthreads();
        if (s_run >= eq) break;
    }
}

// ---------------- BCE over selected ----------------
__global__ __launch_bounds__(256) void kBCE(const float* __restrict__ lcpp,
                                            const unsigned char* __restrict__ confb,
                                            const float4* __restrict__ cnf,
                                            const unsigned int* __restrict__ sel,
                                            double* __restrict__ acc) {
    const int b = blockIdx.y, tid = threadIdx.x;
    const unsigned int T = sel[384 + b];
    const float* v = lcpp + (size_t)b * NPRI;
    const unsigned char* cb = confb + (size_t)b * NPRI;
    float local = 0.0f;
    const int base = blockIdx.x * 2048 + tid;
    for (int it = 0; it < 8; ++it) {
        const int i = base + it * 256;
        const unsigned int u = __float_as_uint(v[i]);
        const int c = cb[i];
        if (c > 0 || u >= T) {
            const float4 x = cnf[(size_t)b * NPRI + i];
            local += bce1(x.x, c == 0) + bce1(x.y, c == 1) + bce1(x.z, c == 2) + bce1(x.w, c == 3);
        }
    }
    #pragma unroll
    for (int s = 32; s > 0; s >>= 1) local += __shfl_down(local, s, 64);
    __shared__ float sc[4];
    const int lane = tid & 63, w = tid >> 6;
    if (lane == 0) sc[w] = local;
    __syncthreads();
    if (tid == 0) atomicAdd(&acc[1], (double)(sc[0] + sc[1] + sc[2] + sc[3]));
}

// ---------------- finalize ----------------
__global__ void kD(const double* __restrict__ acc, const int* __restrict__ npos,
                   float* __restrict__ out) {
    if (threadIdx.x == 0 && blockIdx.x == 0) {
        int n = 0;
        for (int b = 0; b < BATCH; ++b) n += npos[b];
        const double N = (double)n;
        out[0] = (float)(acc[0] / N);
        out[1] = (float)(acc[1] / N);
        out[2] = (float)(acc[2] / N);
    }
}

extern "C" void kernel_launch(void* const* d_in, const int* in_sizes, int n_in,
                              void* d_out, int out_size, void* d_ws, size_t ws_size,
                              hipStream_t stream) {
    const float* loc = (const float*)d_in[0];
    const float* cnfp = (const float*)d_in[1];
    const float* regp = (const float*)d_in[2];
    const float* tgt = (const float*)d_in[3];
    const float* pri = (const float*)d_in[4];

    char* ws = (char*)d_ws;
    double* acc = (double*)(ws + OFF_ACC);
    int* npos = (int*)(ws + OFF_NPOS);
    unsigned long long* bpk = (unsigned long long*)(ws + OFF_BPK);
    unsigned int* sel = (unsigned int*)(ws + OFF_SEL);
    unsigned int* hist2 = (unsigned int*)(ws + OFF_H2);
    unsigned int* hist3 = (unsigned int*)(ws + OFF_H3);
    float* lcpp = (float*)(ws + OFF_LCPP);
    unsigned char* confb = (unsigned char*)(ws + OFF_CONF);
    unsigned int* hist1 = (unsigned int*)(ws + OFF_H1);

    hipMemsetAsync(ws, 0, 24576, stream);
    hipMemsetAsync(ws + OFF_H1, 0, H1_BYTES, stream);

    kA<<<dim3(8, BATCH), 256, 0, stream>>>(tgt, (const float4*)pri, bpk);
    kB<<<dim3(NPRI / 256, BATCH), 256, 0, stream>>>(tgt, (const float4*)pri, (const float2*)loc,
                                                    (const float4*)cnfp, regp, bpk, lcpp, confb,
                                                    hist1, acc, npos);
    kS1<<<BATCH, 256, 0, stream>>>(hist1, npos, hist2, sel);
    kH2<<<dim3(8, BATCH), 256, 0, stream>>>(lcpp, sel, hist2);
    kS2<<<BATCH, 256, 0, stream>>>(hist2, hist3, sel);
    kH3<<<dim3(8, BATCH), 256, 0, stream>>>(lcpp, sel, hist3);
    kS3<<<BATCH, 256, 0, stream>>>(hist3, sel);
    kTie<<<BATCH, 256, 0, stream>>>(lcpp, sel);
    kBCE<<<dim3(16, BATCH), 256, 0, stream>>>(lcpp, confb, (const float4*)cnfp, sel, acc);
    kD<<<1, 64, 0, stream>>>(acc, npos, (float*)d_out);
}

// Round 3
// 529.892 us; speedup vs baseline: 1.6768x; 1.0452x over previous
//
#include <hip/hip_runtime.h>
#include <math.h>

#define BATCH 128
#define NPRI  32768
#define NOBJ  20
#define THRSH 0.5f
#define VARNC 0.1f

// ---- workspace layout ----
#define OFF_ACC  0                      // 3 doubles
#define OFF_NPOS 64                     // 128 ints
#define OFF_BPK  1024                   // 2560 ull
#define OFF_SEL  21504                  // uint sel[768]: [384]T [512]REM [640]EQ
#define OFF_LCPP (1 << 19)              // 16 MB float
#define OFF_CONF (OFF_LCPP + 4 * BATCH * NPRI)   // 4 MB bytes

__device__ __forceinline__ float sl1(float d) {
    d = fabsf(d);
    return (d < 1.0f) ? 0.5f * d * d : d - 0.5f;
}
__device__ __forceinline__ float bce1(float x, bool hot) {
    float tgt = hot ? 0.925f : 0.025f;
    return fmaxf(x, 0.0f) - x * tgt + log1pf(expf(-fabsf(x)));
}

// ---------------- kA: per-truth best prior (16 priors/thread) ----------------
__global__ __launch_bounds__(256) void kA(const float* __restrict__ targets,
                                          const float4* __restrict__ priors,
                                          unsigned long long* __restrict__ bpk) {
    const int b = blockIdx.y;
    const int tid = threadIdx.x;
    float t0[NOBJ], t1[NOBJ], t2[NOBJ], t3[NOBJ], aa[NOBJ];
    #pragma unroll
    for (int o = 0; o < NOBJ; ++o) {
        const float* t = targets + (b * NOBJ + o) * 6;
        t0[o] = t[0]; t1[o] = t[1]; t2[o] = t[2]; t3[o] = t[3];
        aa[o] = (t2[o] - t0[o]) * (t3[o] - t1[o]);
    }
    float best[NOBJ]; int bp[NOBJ];
    #pragma unroll
    for (int o = 0; o < NOBJ; ++o) { best[o] = -1.0f; bp[o] = 0; }

    for (int it = 0; it < 16; ++it) {
        const int p = blockIdx.x * 4096 + it * 256 + tid;
        const float4 pr = priors[p];
        const float px0 = pr.x - pr.z * 0.5f, py0 = pr.y - pr.w * 0.5f;
        const float px1 = pr.x + pr.z * 0.5f, py1 = pr.y + pr.w * 0.5f;
        const float areab = (px1 - px0) * (py1 - py0);
        #pragma unroll
        for (int o = 0; o < NOBJ; ++o) {
            float ix = fminf(t2[o], px1) - fmaxf(t0[o], px0); ix = fmaxf(ix, 0.0f);
            float iy = fminf(t3[o], py1) - fmaxf(t1[o], py0); iy = fmaxf(iy, 0.0f);
            const float inter = ix * iy;
            const float iou = inter / (aa[o] + areab - inter);
            if (iou > best[o]) { best[o] = iou; bp[o] = p; }   // ascending p: first max = min idx
        }
    }
    __shared__ unsigned long long skey[NOBJ];
    if (tid < NOBJ) skey[tid] = 0ull;
    __syncthreads();
    const int lane = tid & 63;
    #pragma unroll
    for (int o = 0; o < NOBJ; ++o) {
        unsigned long long key = ((unsigned long long)__float_as_uint(best[o]) << 32)
                               | (unsigned long long)(0xFFFFFFFFu - (unsigned)bp[o]);
        #pragma unroll
        for (int s = 32; s > 0; s >>= 1) {
            unsigned long long k2 = __shfl_xor(key, s, 64);
            if (k2 > key) key = k2;
        }
        if (lane == 0) atomicMax(&skey[o], key);
    }
    __syncthreads();
    if (tid < NOBJ) atomicMax(&bpk[b * NOBJ + tid], skey[tid]);
}

// ---------------- kB: match + loc/reg losses + loss_cpp (NO histogram) ----------------
__global__ __launch_bounds__(256) void kB(const float* __restrict__ targets,
                                          const float4* __restrict__ priors,
                                          const float2* __restrict__ loc,
                                          const float4* __restrict__ cnf,
                                          const float* __restrict__ reg,
                                          const unsigned long long* __restrict__ bpk,
                                          float* __restrict__ lcpp,
                                          unsigned char* __restrict__ confb,
                                          double* __restrict__ acc,
                                          int* __restrict__ npos) {
    const int b = blockIdx.y;
    const int p = blockIdx.x * 256 + threadIdx.x;
    const float* tb = targets + b * NOBJ * 6;            // block-uniform -> s_loads
    const unsigned long long* bb = bpk + b * NOBJ;       // block-uniform -> s_loads

    const float4 pr = priors[p];
    const float px0 = pr.x - pr.z * 0.5f, py0 = pr.y - pr.w * 0.5f;
    const float px1 = pr.x + pr.z * 0.5f, py1 = pr.y + pr.w * 0.5f;
    const float areab = (px1 - px0) * (py1 - py0);

    // cross-multiply argmax: avoids 20 divisions; strict > keeps first occurrence
    float binter = -1.0f, bden = 1.0f; int bti = 0;
    #pragma unroll
    for (int o = 0; o < NOBJ; ++o) {
        const float t0 = tb[o * 6], t1 = tb[o * 6 + 1], t2 = tb[o * 6 + 2], t3 = tb[o * 6 + 3];
        float ix = fminf(t2, px1) - fmaxf(t0, px0); ix = fmaxf(ix, 0.0f);
        float iy = fminf(t3, py1) - fmaxf(t1, py0); iy = fmaxf(iy, 0.0f);
        const float inter = ix * iy;
        const float den = (t2 - t0) * (t3 - t1) + areab - inter;
        if (inter * bden > binter * den) { binter = inter; bden = den; bti = o; }
    }
    float bto = binter / bden;
    #pragma unroll
    for (int o = 0; o < NOBJ; ++o) {                     // serial scatter override, last o wins
        const int bpi = (int)(0xFFFFFFFFu - (unsigned)(bb[o] & 0xFFFFFFFFull));
        if (bpi == p) { bto = 2.0f; bti = o; }
    }

    const float* tsel = tb + bti * 6;                    // 6 scattered loads, L1-resident
    int c = 0;
    if (bto >= THRSH) c = (int)tsel[4];
    const bool pos = c > 0;

    const float4 x = cnf[(size_t)b * NPRI + p];
    const float m = fmaxf(fmaxf(x.x, x.y), fmaxf(x.z, x.w));
    const float lse = m + logf(expf(x.x - m) + expf(x.y - m) + expf(x.z - m) + expf(x.w - m));
    const float picked = (c == 0) ? x.x : (c == 1) ? x.y : (c == 2) ? x.z : x.w;
    const float lval = pos ? 0.0f : (lse - picked);
    lcpp[(size_t)b * NPRI + p] = lval;
    confb[(size_t)b * NPRI + p] = (unsigned char)c;

    float ll = 0.0f, lr = 0.0f; int np = 0;
    if (pos) {
        const float cx = (tsel[0] + tsel[2]) * 0.5f, cy = (tsel[1] + tsel[3]) * 0.5f;
        const float lt0 = (cx - pr.x) / (VARNC * pr.z);
        const float lt1 = (cy - pr.y) / (VARNC * pr.w);
        const float2 ld = loc[(size_t)b * NPRI + p];
        ll = sl1(ld.x - lt0) + sl1(ld.y - lt1);
        lr = sl1(reg[(size_t)b * NPRI + p] - tsel[5]);
        np = 1;
    }
    #pragma unroll
    for (int s = 32; s > 0; s >>= 1) {
        ll += __shfl_down(ll, s, 64);
        lr += __shfl_down(lr, s, 64);
        np += __shfl_down(np, s, 64);
    }
    __shared__ float sred[4][2];
    __shared__ int sredn[4];
    const int lane = threadIdx.x & 63, w = threadIdx.x >> 6;
    if (lane == 0) { sred[w][0] = ll; sred[w][1] = lr; sredn[w] = np; }
    __syncthreads();
    if (threadIdx.x == 0) {
        const float tl = sred[0][0] + sred[1][0] + sred[2][0] + sred[3][0];
        const float tr = sred[0][1] + sred[1][1] + sred[2][1] + sred[3][1];
        const int tn = sredn[0] + sredn[1] + sredn[2] + sredn[3];
        if (tn) {
            atomicAdd(&acc[0], (double)tl);
            atomicAdd(&acc[2], (double)tr);
            atomicAdd(&npos[b], tn);
        }
    }
}

// ---- wave-aggregated LDS histogram add (handles hot bins without serialization)
__device__ __forceinline__ void waveAgg(unsigned int* h, unsigned bin, int lane) {
    unsigned long long todo = __ballot(1);
    while (todo) {
        const int leader = __builtin_ctzll(todo);
        const unsigned lb = (unsigned)__shfl((int)bin, leader, 64);
        const unsigned long long m = __ballot(bin == lb);
        if (lane == leader) atomicAdd(&h[lb], (unsigned)__popcll(m));
        todo &= ~m;
    }
}

// ---- parallel descending-rank select over 256 bins; returns bin + new r via res[]
__device__ __forceinline__ void selScan(unsigned int* h, unsigned int* scan, int* res,
                                        int r, int tid) {
    scan[tid] = h[tid];
    __syncthreads();
    #pragma unroll
    for (int off = 1; off < 256; off <<= 1) {
        const unsigned add = (tid + off < 256) ? scan[tid + off] : 0u;
        __syncthreads();
        scan[tid] += add;
        __syncthreads();
    }
    const int sfx = (int)scan[tid];                       // suffix sum >= tid
    const int nxt = (tid < 255) ? (int)scan[tid + 1] : 0;
    if (sfx >= r + 1 && nxt < r + 1) { res[0] = tid; res[1] = r - nxt; }
    __syncthreads();
}

// ---------------- kSel: full 32-bit radix select, one block per batch ----------------
__global__ __launch_bounds__(256) void kSel(const float* __restrict__ lcpp,
                                            const int* __restrict__ npos,
                                            unsigned int* __restrict__ sel) {
    const int b = blockIdx.x, tid = threadIdx.x, lane = tid & 63;
    __shared__ unsigned int h[256], scan[256];
    __shared__ int res[2];
    const float4* v4 = (const float4*)(lcpp + (size_t)b * NPRI);

    int k = min(3 * npos[b], NPRI - 1);
    if (k < 1) k = 1;                                     // npos>=20 in practice
    int r = k - 1;
    unsigned P = 0;

    for (int pass = 0; pass < 4; ++pass) {
        h[tid] = 0;
        __syncthreads();
        const int shift = 24 - 8 * pass;
        for (int it = 0; it < NPRI / 4 / 256; ++it) {
            const float4 x = v4[it * 256 + tid];
            const unsigned u0 = __float_as_uint(x.x), u1 = __float_as_uint(x.y);
            const unsigned u2 = __float_as_uint(x.z), u3 = __float_as_uint(x.w);
            if (pass == 0) {                              // hot exponent bins -> wave-aggregate
                waveAgg(h, u0 >> 24, lane);
                waveAgg(h, u1 >> 24, lane);
                waveAgg(h, u2 >> 24, lane);
                waveAgg(h, u3 >> 24, lane);
            } else {                                      // sparse matches -> plain atomics
                const int hs = shift + 8;
                if ((u0 >> hs) == P) atomicAdd(&h[(u0 >> shift) & 255u], 1u);
                if ((u1 >> hs) == P) atomicAdd(&h[(u1 >> shift) & 255u], 1u);
                if ((u2 >> hs) == P) atomicAdd(&h[(u2 >> shift) & 255u], 1u);
                if ((u3 >> hs) == P) atomicAdd(&h[(u3 >> shift) & 255u], 1u);
            }
        }
        __syncthreads();
        selScan(h, scan, res, r, tid);
        const int bsel = res[0];
        r = res[1];
        if (pass == 3 && tid == 0) {
            sel[384 + b] = (P << 8) | (unsigned)bsel;     // exact k-th value T
            sel[512 + b] = (unsigned)(r + 1);             // ties to accept (stable, low index first)
            sel[640 + b] = h[bsel];                       // total tie count
        }
        P = (P << 8) | (unsigned)bsel;
        __syncthreads();
    }
}

// ---------------- kTie: demote excess ties (rare path; stable by index) ----------------
__global__ __launch_bounds__(256) void kTie(float* __restrict__ lcpp,
                                            const unsigned int* __restrict__ sel) {
    const int b = blockIdx.x, tid = threadIdx.x;
    const unsigned int T = sel[384 + b];
    const int rem = (int)sel[512 + b];
    const int eq = (int)sel[640 + b];
    if (eq <= rem || T == 0u) return;
    float* v = lcpp + (size_t)b * NPRI;
    __shared__ int s_run;
    __shared__ int s_wcnt[4];
    if (tid == 0) s_run = 0;
    __syncthreads();
    const int lane = tid & 63, w = tid >> 6;
    for (int chunk = 0; chunk < NPRI / 256; ++chunk) {
        const int i = chunk * 256 + tid;
        const unsigned int u = __float_as_uint(v[i]);
        const bool tie = (u == T);
        const unsigned long long msk = __ballot(tie);
        if (lane == 0) s_wcnt[w] = __popcll(msk);
        __syncthreads();
        int off = 0;
        #pragma unroll
        for (int j = 0; j < 4; ++j) if (j < w) off += s_wcnt[j];
        const int ctot = s_wcnt[0] + s_wcnt[1] + s_wcnt[2] + s_wcnt[3];
        const int myrank = s_run + off + __popcll(msk & ((1ull << lane) - 1ull));
        if (tie && myrank >= rem) v[i] = __uint_as_float(T - 1u);
        __syncthreads();
        if (tid == 0) s_run += ctot;
        __syncthreads();
        if (s_run >= eq) break;
    }
}

// ---------------- BCE over selected ----------------
__global__ __launch_bounds__(256) void kBCE(const float* __restrict__ lcpp,
                                            const unsigned char* __restrict__ confb,
                                            const float4* __restrict__ cnf,
                                            const unsigned int* __restrict__ sel,
                                            double* __restrict__ acc) {
    const int b = blockIdx.y, tid = threadIdx.x;
    const unsigned int T = sel[384 + b];
    const float* v = lcpp + (size_t)b * NPRI;
    const unsigned char* cb = confb + (size_t)b * NPRI;
    float local = 0.0f;
    const int base = blockIdx.x * 2048 + tid;
    for (int it = 0; it < 8; ++it) {
        const int i = base + it * 256;
        const unsigned int u = __float_as_uint(v[i]);
        const int c = cb[i];
        if (c > 0 || u >= T) {
            const float4 x = cnf[(size_t)b * NPRI + i];
            local += bce1(x.x, c == 0) + bce1(x.y, c == 1) + bce1(x.z, c == 2) + bce1(x.w, c == 3);
        }
    }
    #pragma unroll
    for (int s = 32; s > 0; s >>= 1) local += __shfl_down(local, s, 64);
    __shared__ float sc[4];
    const int lane = tid & 63, w = tid >> 6;
    if (lane == 0) sc[w] = local;
    __syncthreads();
    if (tid == 0) atomicAdd(&acc[1], (double)(sc[0] + sc[1] + sc[2] + sc[3]));
}

// ---------------- finalize ----------------
__global__ void kD(const double* __restrict__ acc, const int* __restrict__ npos,
                   float* __restrict__ out) {
    if (threadIdx.x == 0 && blockIdx.x == 0) {
        int n = 0;
        for (int b = 0; b < BATCH; ++b) n += npos[b];
        const double N = (double)n;
        out[0] = (float)(acc[0] / N);
        out[1] = (float)(acc[1] / N);
        out[2] = (float)(acc[2] / N);
    }
}

extern "C" void kernel_launch(void* const* d_in, const int* in_sizes, int n_in,
                              void* d_out, int out_size, void* d_ws, size_t ws_size,
                              hipStream_t stream) {
    const float* loc = (const float*)d_in[0];
    const float* cnfp = (const float*)d_in[1];
    const float* regp = (const float*)d_in[2];
    const float* tgt = (const float*)d_in[3];
    const float* pri = (const float*)d_in[4];

    char* ws = (char*)d_ws;
    double* acc = (double*)(ws + OFF_ACC);
    int* npos = (int*)(ws + OFF_NPOS);
    unsigned long long* bpk = (unsigned long long*)(ws + OFF_BPK);
    unsigned int* sel = (unsigned int*)(ws + OFF_SEL);
    float* lcpp = (float*)(ws + OFF_LCPP);
    unsigned char* confb = (unsigned char*)(ws + OFF_CONF);

    hipMemsetAsync(ws, 0, 24576, stream);   // acc/npos/bpk/sel header

    kA<<<dim3(8, BATCH), 256, 0, stream>>>(tgt, (const float4*)pri, bpk);
    kB<<<dim3(NPRI / 256, BATCH), 256, 0, stream>>>(tgt, (const float4*)pri, (const float2*)loc,
                                                    (const float4*)cnfp, regp, bpk, lcpp, confb,
                                                    acc, npos);
    kSel<<<BATCH, 256, 0, stream>>>(lcpp, npos, sel);
    kTie<<<BATCH, 256, 0, stream>>>(lcpp, sel);
    kBCE<<<dim3(16, BATCH), 256, 0, stream>>>(lcpp, confb, (const float4*)cnfp, sel, acc);
    kD<<<1, 64, 0, stream>>>(acc, npos, (float*)d_out);
}

// Round 4
// 422.506 us; speedup vs baseline: 2.1030x; 1.2542x over previous
//
#include <hip/hip_runtime.h>
#include <math.h>

#define BATCH 128
#define NPRI  32768
#define NOBJ  20
#define THRSH 0.5f
#define VARNC 0.1f

// ---- workspace layout ----
#define OFF_ACC  0                      // 3 doubles (0..24)
#define OFF_DONE 48                     // int: kBCE completion counter
#define OFF_NTOT 56                     // int: total num_pos
#define OFF_NPOS 64                     // 128 ints
#define OFF_BPK  1024                   // 2560 ull -> ends at 21504
#define OFF_SEL  21504                  // uint sel[256]: [0..128)=T, [128..256)=Istar
#define OFF_LCPP (1 << 19)              // 16 MB float
#define OFF_CONF (OFF_LCPP + 4 * BATCH * NPRI)   // 4 MB bytes

__device__ __forceinline__ float sl1(float d) {
    d = fabsf(d);
    return (d < 1.0f) ? 0.5f * d * d : d - 0.5f;
}
__device__ __forceinline__ float bce1(float x, bool hot) {
    float tgt = hot ? 0.925f : 0.025f;
    return fmaxf(x, 0.0f) - x * tgt + log1pf(expf(-fabsf(x)));
}

// ---------------- kA: per-truth best prior (16 priors/thread) ----------------
__global__ __launch_bounds__(256) void kA(const float* __restrict__ targets,
                                          const float4* __restrict__ priors,
                                          unsigned long long* __restrict__ bpk) {
    const int b = blockIdx.y;
    const int tid = threadIdx.x;
    float t0[NOBJ], t1[NOBJ], t2[NOBJ], t3[NOBJ], aa[NOBJ];
    #pragma unroll
    for (int o = 0; o < NOBJ; ++o) {
        const float* t = targets + (b * NOBJ + o) * 6;
        t0[o] = t[0]; t1[o] = t[1]; t2[o] = t[2]; t3[o] = t[3];
        aa[o] = (t2[o] - t0[o]) * (t3[o] - t1[o]);
    }
    float best[NOBJ]; int bp[NOBJ];
    #pragma unroll
    for (int o = 0; o < NOBJ; ++o) { best[o] = -1.0f; bp[o] = 0; }

    for (int it = 0; it < 16; ++it) {
        const int p = blockIdx.x * 4096 + it * 256 + tid;
        const float4 pr = priors[p];
        const float px0 = pr.x - pr.z * 0.5f, py0 = pr.y - pr.w * 0.5f;
        const float px1 = pr.x + pr.z * 0.5f, py1 = pr.y + pr.w * 0.5f;
        const float areab = (px1 - px0) * (py1 - py0);
        #pragma unroll
        for (int o = 0; o < NOBJ; ++o) {
            float ix = fminf(t2[o], px1) - fmaxf(t0[o], px0); ix = fmaxf(ix, 0.0f);
            float iy = fminf(t3[o], py1) - fmaxf(t1[o], py0); iy = fmaxf(iy, 0.0f);
            const float inter = ix * iy;
            const float iou = inter / (aa[o] + areab - inter);
            if (iou > best[o]) { best[o] = iou; bp[o] = p; }   // ascending p: first max = min idx
        }
    }
    __shared__ unsigned long long skey[NOBJ];
    if (tid < NOBJ) skey[tid] = 0ull;
    __syncthreads();
    const int lane = tid & 63;
    #pragma unroll
    for (int o = 0; o < NOBJ; ++o) {
        unsigned long long key = ((unsigned long long)__float_as_uint(best[o]) << 32)
                               | (unsigned long long)(0xFFFFFFFFu - (unsigned)bp[o]);
        #pragma unroll
        for (int s = 32; s > 0; s >>= 1) {
            unsigned long long k2 = __shfl_xor(key, s, 64);
            if (k2 > key) key = k2;
        }
        if (lane == 0) atomicMax(&skey[o], key);
    }
    __syncthreads();
    if (tid < NOBJ) atomicMax(&bpk[b * NOBJ + tid], skey[tid]);
}

// ---------------- kB: 4 priors/thread, match + losses + loss_cpp ----------------
__global__ __launch_bounds__(256) void kB(const float* __restrict__ targets,
                                          const float4* __restrict__ priors,
                                          const float2* __restrict__ loc,
                                          const float4* __restrict__ cnf,
                                          const float* __restrict__ reg,
                                          const unsigned long long* __restrict__ bpk,
                                          float* __restrict__ lcpp,
                                          unsigned char* __restrict__ confb,
                                          double* __restrict__ acc,
                                          int* __restrict__ npos,
                                          int* __restrict__ ntot) {
    const int b = blockIdx.y;
    const int tid = threadIdx.x;
    const int base = blockIdx.x * 1024;
    const float* tb = targets + b * NOBJ * 6;            // block-uniform -> s_loads
    const unsigned long long* bb = bpk + b * NOBJ;

    // hoisted global loads: 4 priors + 4 cnf vectors in flight before the VALU storm
    float4 pr[4], x[4];
    #pragma unroll
    for (int j = 0; j < 4; ++j) {
        pr[j] = priors[base + j * 256 + tid];
        x[j] = cnf[(size_t)b * NPRI + base + j * 256 + tid];
    }
    float px0[4], py0[4], px1[4], py1[4], ab[4];
    #pragma unroll
    for (int j = 0; j < 4; ++j) {
        px0[j] = pr[j].x - pr[j].z * 0.5f; py0[j] = pr[j].y - pr[j].w * 0.5f;
        px1[j] = pr[j].x + pr[j].z * 0.5f; py1[j] = pr[j].y + pr[j].w * 0.5f;
        ab[j] = (px1[j] - px0[j]) * (py1[j] - py0[j]);
    }
    float bi[4], bd[4]; int bt[4];
    #pragma unroll
    for (int j = 0; j < 4; ++j) { bi[j] = -1.0f; bd[j] = 1.0f; bt[j] = 0; }

    #pragma unroll
    for (int o = 0; o < NOBJ; ++o) {
        const float t0 = tb[o * 6], t1 = tb[o * 6 + 1], t2 = tb[o * 6 + 2], t3 = tb[o * 6 + 3];
        const float aa = (t2 - t0) * (t3 - t1);
        #pragma unroll
        for (int j = 0; j < 4; ++j) {
            float ix = fminf(t2, px1[j]) - fmaxf(t0, px0[j]); ix = fmaxf(ix, 0.0f);
            float iy = fminf(t3, py1[j]) - fmaxf(t1, py0[j]); iy = fmaxf(iy, 0.0f);
            const float inter = ix * iy;
            const float den = aa + ab[j] - inter;
            if (inter * bd[j] > bi[j] * den) { bi[j] = inter; bd[j] = den; bt[j] = o; }
        }
    }
    float bto[4];
    #pragma unroll
    for (int j = 0; j < 4; ++j) bto[j] = bi[j] / bd[j];
    #pragma unroll
    for (int o = 0; o < NOBJ; ++o) {                     // serial scatter override, last o wins
        const int bpi = (int)(0xFFFFFFFFu - (unsigned)(bb[o] & 0xFFFFFFFFull));
        #pragma unroll
        for (int j = 0; j < 4; ++j)
            if (bpi == base + j * 256 + tid) { bto[j] = 2.0f; bt[j] = o; }
    }

    float ll = 0.0f, lr = 0.0f; int np = 0;
    #pragma unroll
    for (int j = 0; j < 4; ++j) {
        const int p = base + j * 256 + tid;
        const float* ts = tb + bt[j] * 6;
        int c = 0;
        if (bto[j] >= THRSH) c = (int)ts[4];
        const float m = fmaxf(fmaxf(x[j].x, x[j].y), fmaxf(x[j].z, x[j].w));
        const float lse = m + logf(expf(x[j].x - m) + expf(x[j].y - m) +
                                   expf(x[j].z - m) + expf(x[j].w - m));
        const float picked = (c == 0) ? x[j].x : (c == 1) ? x[j].y : (c == 2) ? x[j].z : x[j].w;
        lcpp[(size_t)b * NPRI + p] = (c > 0) ? 0.0f : (lse - picked);
        confb[(size_t)b * NPRI + p] = (unsigned char)c;
        if (c > 0) {
            const float cx = (ts[0] + ts[2]) * 0.5f, cy = (ts[1] + ts[3]) * 0.5f;
            const float lt0 = (cx - pr[j].x) / (VARNC * pr[j].z);
            const float lt1 = (cy - pr[j].y) / (VARNC * pr[j].w);
            const float2 ld = loc[(size_t)b * NPRI + p];
            ll += sl1(ld.x - lt0) + sl1(ld.y - lt1);
            lr += sl1(reg[(size_t)b * NPRI + p] - ts[5]);
            ++np;
        }
    }
    #pragma unroll
    for (int s = 32; s > 0; s >>= 1) {
        ll += __shfl_down(ll, s, 64);
        lr += __shfl_down(lr, s, 64);
        np += __shfl_down(np, s, 64);
    }
    __shared__ float sred[4][2];
    __shared__ int sredn[4];
    const int lane = tid & 63, w = tid >> 6;
    if (lane == 0) { sred[w][0] = ll; sred[w][1] = lr; sredn[w] = np; }
    __syncthreads();
    if (tid == 0) {
        const float tl = sred[0][0] + sred[1][0] + sred[2][0] + sred[3][0];
        const float tr = sred[0][1] + sred[1][1] + sred[2][1] + sred[3][1];
        const int tn = sredn[0] + sredn[1] + sredn[2] + sredn[3];
        if (tn) {
            atomicAdd(&acc[0], (double)tl);
            atomicAdd(&acc[2], (double)tr);
            atomicAdd(&npos[b], tn);
            atomicAdd(ntot, tn);
        }
    }
}

// ---- wave-aggregated LDS histogram add (handles hot bins without serialization)
__device__ __forceinline__ void waveAgg(unsigned int* h, unsigned bin, int lane) {
    unsigned long long todo = __ballot(1);
    while (todo) {
        const int leader = __builtin_ctzll(todo);
        const unsigned lb = (unsigned)__shfl((int)bin, leader, 64);
        const unsigned long long m = __ballot(bin == lb);
        if (lane == leader) atomicAdd(&h[lb], (unsigned)__popcll(m));
        todo &= ~m;
    }
}

// ---------------- kSel: 32-bit radix select + tie-cutoff index, 1024 thr/block ----------------
__global__ __launch_bounds__(1024) void kSel(const float* __restrict__ lcpp,
                                             const int* __restrict__ npos,
                                             unsigned int* __restrict__ sel) {
    const int b = blockIdx.x, tid = threadIdx.x, lane = tid & 63, w = tid >> 6;
    __shared__ unsigned int h[256], scan[256];
    __shared__ int res[2];
    __shared__ int wsum[16];
    __shared__ int srun;
    __shared__ int sIstar;
    const float4* v4 = (const float4*)(lcpp + (size_t)b * NPRI);

    int k = min(3 * npos[b], NPRI - 1);
    if (k < 1) k = 1;
    int r = k - 1;
    unsigned P = 0, eq = 0;

    for (int pass = 0; pass < 4; ++pass) {
        if (tid < 256) h[tid] = 0;
        __syncthreads();
        const int shift = 24 - 8 * pass;
        for (int it = 0; it < NPRI / 4 / 1024; ++it) {     // 8 float4 per thread
            const float4 xx = v4[it * 1024 + tid];
            const unsigned u0 = __float_as_uint(xx.x), u1 = __float_as_uint(xx.y);
            const unsigned u2 = __float_as_uint(xx.z), u3 = __float_as_uint(xx.w);
            if (pass == 0) {
                waveAgg(h, u0 >> 24, lane);
                waveAgg(h, u1 >> 24, lane);
                waveAgg(h, u2 >> 24, lane);
                waveAgg(h, u3 >> 24, lane);
            } else {
                const int hs = shift + 8;
                if ((u0 >> hs) == P) atomicAdd(&h[(u0 >> shift) & 255u], 1u);
                if ((u1 >> hs) == P) atomicAdd(&h[(u1 >> shift) & 255u], 1u);
                if ((u2 >> hs) == P) atomicAdd(&h[(u2 >> shift) & 255u], 1u);
                if ((u3 >> hs) == P) atomicAdd(&h[(u3 >> shift) & 255u], 1u);
            }
        }
        __syncthreads();
        if (tid < 256) scan[tid] = h[tid];
        __syncthreads();
        #pragma unroll
        for (int off = 1; off < 256; off <<= 1) {
            unsigned add = 0;
            if (tid < 256 && tid + off < 256) add = scan[tid + off];
            __syncthreads();
            if (tid < 256) scan[tid] += add;
            __syncthreads();
        }
        if (tid < 256) {
            const int sfx = (int)scan[tid];
            const int nxt = (tid < 255) ? (int)scan[tid + 1] : 0;
            if (sfx >= r + 1 && nxt < r + 1) { res[0] = tid; res[1] = r - nxt; }
        }
        __syncthreads();
        const int bsel = res[0];
        r = res[1];
        if (pass == 3) eq = h[bsel];
        P = (P << 8) | (unsigned)bsel;
        __syncthreads();
    }
    const unsigned T = P;
    const int rem = r + 1;
    int Istar = 0x7FFFFFFF;                               // all ties selected
    if ((int)eq > rem) {                                  // rare: excess ties, stable cutoff
        if (tid == 0) { srun = 0; sIstar = 0x7FFFFFFF; }
        __syncthreads();
        const float* v = (const float*)v4;
        for (int chunk = 0; chunk < NPRI / 1024; ++chunk) {
            const int i = chunk * 1024 + tid;
            const bool tie = (__float_as_uint(v[i]) == T);
            const unsigned long long msk = __ballot(tie);
            if (lane == 0) wsum[w] = __popcll(msk);
            __syncthreads();
            int pre = 0, tot = 0;
            #pragma unroll
            for (int q = 0; q < 16; ++q) { const int c = wsum[q]; if (q < w) pre += c; tot += c; }
            const int myrank = srun + pre + __popcll(msk & ((1ull << lane) - 1ull));
            if (tie && myrank == rem - 1) sIstar = i;     // index of last accepted tie
            __syncthreads();
            if (tid == 0) srun += tot;
            __syncthreads();
            if (srun >= rem) break;                       // uniform
        }
        Istar = sIstar;
    }
    if (tid == 0) { sel[b] = T; sel[128 + b] = (unsigned)Istar; }
}

// ---------------- kBCE: BCE over selected + last-block finalize ----------------
__global__ __launch_bounds__(256) void kBCE(const float* __restrict__ lcpp,
                                            const unsigned char* __restrict__ confb,
                                            const float4* __restrict__ cnf,
                                            const unsigned int* __restrict__ sel,
                                            double* __restrict__ acc,
                                            int* __restrict__ ntot,
                                            int* __restrict__ done,
                                            float* __restrict__ out) {
    const int b = blockIdx.y, tid = threadIdx.x;
    const unsigned int T = sel[b];
    const int Istar = (int)sel[128 + b];
    const float* v = lcpp + (size_t)b * NPRI;
    const unsigned char* cb = confb + (size_t)b * NPRI;
    float local = 0.0f;
    const int base = blockIdx.x * 2048 + tid;
    for (int it = 0; it < 8; ++it) {
        const int i = base + it * 256;
        const unsigned int u = __float_as_uint(v[i]);
        const int c = cb[i];
        if (c > 0 || u > T || (u == T && i <= Istar)) {
            const float4 x = cnf[(size_t)b * NPRI + i];
            local += bce1(x.x, c == 0) + bce1(x.y, c == 1) + bce1(x.z, c == 2) + bce1(x.w, c == 3);
        }
    }
    #pragma unroll
    for (int s = 32; s > 0; s >>= 1) local += __shfl_down(local, s, 64);
    __shared__ float sc[4];
    const int lane = tid & 63, w = tid >> 6;
    if (lane == 0) sc[w] = local;
    __syncthreads();
    __shared__ bool slast;
    if (tid == 0) {
        atomicAdd(&acc[1], (double)(sc[0] + sc[1] + sc[2] + sc[3]));
        __threadfence();
        const int old = atomicAdd(done, 1);
        slast = (old == 16 * BATCH - 1);
    }
    __syncthreads();
    if (slast && tid == 0) {
        __threadfence();
        const double a0 = atomicAdd(&acc[0], 0.0);        // atomic-RMW read: cross-XCD safe
        const double a1 = atomicAdd(&acc[1], 0.0);
        const double a2 = atomicAdd(&acc[2], 0.0);
        const int n = atomicAdd(ntot, 0);
        const double N = (double)n;
        out[0] = (float)(a0 / N);
        out[1] = (float)(a1 / N);
        out[2] = (float)(a2 / N);
    }
}

extern "C" void kernel_launch(void* const* d_in, const int* in_sizes, int n_in,
                              void* d_out, int out_size, void* d_ws, size_t ws_size,
                              hipStream_t stream) {
    const float* loc = (const float*)d_in[0];
    const float* cnfp = (const float*)d_in[1];
    const float* regp = (const float*)d_in[2];
    const float* tgt = (const float*)d_in[3];
    const float* pri = (const float*)d_in[4];

    char* ws = (char*)d_ws;
    double* acc = (double*)(ws + OFF_ACC);
    int* done = (int*)(ws + OFF_DONE);
    int* ntot = (int*)(ws + OFF_NTOT);
    int* npos = (int*)(ws + OFF_NPOS);
    unsigned long long* bpk = (unsigned long long*)(ws + OFF_BPK);
    unsigned int* sel = (unsigned int*)(ws + OFF_SEL);
    float* lcpp = (float*)(ws + OFF_LCPP);
    unsigned char* confb = (unsigned char*)(ws + OFF_CONF);

    hipMemsetAsync(ws, 0, 24576, stream);   // acc/done/ntot/npos/bpk/sel header

    kA<<<dim3(8, BATCH), 256, 0, stream>>>(tgt, (const float4*)pri, bpk);
    kB<<<dim3(NPRI / 1024, BATCH), 256, 0, stream>>>(tgt, (const float4*)pri, (const float2*)loc,
                                                     (const float4*)cnfp, regp, bpk, lcpp, confb,
                                                     acc, npos, ntot);
    kSel<<<BATCH, 1024, 0, stream>>>(lcpp, npos, sel);
    kBCE<<<dim3(16, BATCH), 256, 0, stream>>>(lcpp, confb, (const float4*)cnfp, sel, acc,
                                              ntot, done, (float*)d_out);
}

// Round 5
// 414.008 us; speedup vs baseline: 2.1461x; 1.0205x over previous
//
#include <hip/hip_runtime.h>
#include <math.h>

#define BATCH 128
#define NPRI  32768
#define NOBJ  20
#define THRSH 0.5f
#define VARNC 0.1f

// ---- workspace layout ----
#define OFF_ACC  0                      // 3 doubles (0..24)
#define OFF_DONE 48                     // int: kSelBCE completion counter
#define OFF_NPOS 64                     // 128 ints
#define OFF_BPK  1024                   // 2560 ull -> ends at 21504
#define OFF_LCPP (1 << 19)              // 16 MB float
#define OFF_CONF (OFF_LCPP + 4 * BATCH * NPRI)   // 4 MB bytes
#define HDR_BYTES 21504

__device__ __forceinline__ float sl1(float d) {
    d = fabsf(d);
    return (d < 1.0f) ? 0.5f * d * d : d - 0.5f;
}
__device__ __forceinline__ float bce1(float x, bool hot) {
    float tgt = hot ? 0.925f : 0.025f;
    return fmaxf(x, 0.0f) - x * tgt + log1pf(expf(-fabsf(x)));
}

// ---------------- kA: per-truth best prior (16 priors/thread) ----------------
__global__ __launch_bounds__(256) void kA(const float* __restrict__ targets,
                                          const float4* __restrict__ priors,
                                          unsigned long long* __restrict__ bpk) {
    const int b = blockIdx.y;
    const int tid = threadIdx.x;
    float t0[NOBJ], t1[NOBJ], t2[NOBJ], t3[NOBJ], aa[NOBJ];
    #pragma unroll
    for (int o = 0; o < NOBJ; ++o) {
        const float* t = targets + (b * NOBJ + o) * 6;
        t0[o] = t[0]; t1[o] = t[1]; t2[o] = t[2]; t3[o] = t[3];
        aa[o] = (t2[o] - t0[o]) * (t3[o] - t1[o]);
    }
    float best[NOBJ]; int bp[NOBJ];
    #pragma unroll
    for (int o = 0; o < NOBJ; ++o) { best[o] = -1.0f; bp[o] = 0; }

    for (int it = 0; it < 16; ++it) {
        const int p = blockIdx.x * 4096 + it * 256 + tid;
        const float4 pr = priors[p];
        const float px0 = pr.x - pr.z * 0.5f, py0 = pr.y - pr.w * 0.5f;
        const float px1 = pr.x + pr.z * 0.5f, py1 = pr.y + pr.w * 0.5f;
        const float areab = (px1 - px0) * (py1 - py0);
        #pragma unroll
        for (int o = 0; o < NOBJ; ++o) {
            float ix = fminf(t2[o], px1) - fmaxf(t0[o], px0); ix = fmaxf(ix, 0.0f);
            float iy = fminf(t3[o], py1) - fmaxf(t1[o], py0); iy = fmaxf(iy, 0.0f);
            const float inter = ix * iy;
            const float iou = inter / (aa[o] + areab - inter);
            if (iou > best[o]) { best[o] = iou; bp[o] = p; }   // ascending p: first max = min idx
        }
    }
    __shared__ unsigned long long skey[NOBJ];
    if (tid < NOBJ) skey[tid] = 0ull;
    __syncthreads();
    const int lane = tid & 63;
    #pragma unroll
    for (int o = 0; o < NOBJ; ++o) {
        unsigned long long key = ((unsigned long long)__float_as_uint(best[o]) << 32)
                               | (unsigned long long)(0xFFFFFFFFu - (unsigned)bp[o]);
        #pragma unroll
        for (int s = 32; s > 0; s >>= 1) {
            unsigned long long k2 = __shfl_xor(key, s, 64);
            if (k2 > key) key = k2;
        }
        if (lane == 0) atomicMax(&skey[o], key);
    }
    __syncthreads();
    if (tid < NOBJ) atomicMax(&bpk[b * NOBJ + tid], skey[tid]);
}

// ---------------- kB: 4 priors/thread, match + losses + loss_cpp ----------------
__global__ __launch_bounds__(256) void kB(const float* __restrict__ targets,
                                          const float4* __restrict__ priors,
                                          const float2* __restrict__ loc,
                                          const float4* __restrict__ cnf,
                                          const float* __restrict__ reg,
                                          const unsigned long long* __restrict__ bpk,
                                          float* __restrict__ lcpp,
                                          unsigned char* __restrict__ confb,
                                          double* __restrict__ acc,
                                          int* __restrict__ npos) {
    const int b = blockIdx.y;
    const int tid = threadIdx.x;
    const int base = blockIdx.x * 1024;
    const float* tb = targets + b * NOBJ * 6;            // block-uniform -> s_loads
    const unsigned long long* bb = bpk + b * NOBJ;

    // priors first (IoU needs them), cnf after (stays in flight behind the VALU storm)
    float4 pr[4];
    #pragma unroll
    for (int j = 0; j < 4; ++j) pr[j] = priors[base + j * 256 + tid];
    float4 x[4];
    #pragma unroll
    for (int j = 0; j < 4; ++j) x[j] = cnf[(size_t)b * NPRI + base + j * 256 + tid];

    float px0[4], py0[4], px1[4], py1[4], ab[4];
    #pragma unroll
    for (int j = 0; j < 4; ++j) {
        px0[j] = pr[j].x - pr[j].z * 0.5f; py0[j] = pr[j].y - pr[j].w * 0.5f;
        px1[j] = pr[j].x + pr[j].z * 0.5f; py1[j] = pr[j].y + pr[j].w * 0.5f;
        ab[j] = (px1[j] - px0[j]) * (py1[j] - py0[j]);
    }
    float bi[4], bd[4]; int bt[4];
    #pragma unroll
    for (int j = 0; j < 4; ++j) { bi[j] = -1.0f; bd[j] = 1.0f; bt[j] = 0; }

    #pragma unroll
    for (int o = 0; o < NOBJ; ++o) {
        const float t0 = tb[o * 6], t1 = tb[o * 6 + 1], t2 = tb[o * 6 + 2], t3 = tb[o * 6 + 3];
        const float aa = (t2 - t0) * (t3 - t1);
        #pragma unroll
        for (int j = 0; j < 4; ++j) {
            float ix = fminf(t2, px1[j]) - fmaxf(t0, px0[j]); ix = fmaxf(ix, 0.0f);
            float iy = fminf(t3, py1[j]) - fmaxf(t1, py0[j]); iy = fmaxf(iy, 0.0f);
            const float inter = ix * iy;
            const float den = aa + ab[j] - inter;
            if (inter * bd[j] > bi[j] * den) { bi[j] = inter; bd[j] = den; bt[j] = o; }
        }
    }
    float bto[4];
    #pragma unroll
    for (int j = 0; j < 4; ++j) bto[j] = bi[j] / bd[j];
    #pragma unroll
    for (int o = 0; o < NOBJ; ++o) {                     // serial scatter override, last o wins
        const int bpi = (int)(0xFFFFFFFFu - (unsigned)(bb[o] & 0xFFFFFFFFull));
        #pragma unroll
        for (int j = 0; j < 4; ++j)
            if (bpi == base + j * 256 + tid) { bto[j] = 2.0f; bt[j] = o; }
    }

    float ll = 0.0f, lr = 0.0f; int np = 0;
    #pragma unroll
    for (int j = 0; j < 4; ++j) {
        const int p = base + j * 256 + tid;
        const float* ts = tb + bt[j] * 6;
        int c = 0;
        if (bto[j] >= THRSH) c = (int)ts[4];
        const float m = fmaxf(fmaxf(x[j].x, x[j].y), fmaxf(x[j].z, x[j].w));
        const float lse = m + logf(expf(x[j].x - m) + expf(x[j].y - m) +
                                   expf(x[j].z - m) + expf(x[j].w - m));
        const float picked = (c == 0) ? x[j].x : (c == 1) ? x[j].y : (c == 2) ? x[j].z : x[j].w;
        lcpp[(size_t)b * NPRI + p] = (c > 0) ? 0.0f : (lse - picked);
        confb[(size_t)b * NPRI + p] = (unsigned char)c;
        if (c > 0) {
            const float cx = (ts[0] + ts[2]) * 0.5f, cy = (ts[1] + ts[3]) * 0.5f;
            const float lt0 = (cx - pr[j].x) / (VARNC * pr[j].z);
            const float lt1 = (cy - pr[j].y) / (VARNC * pr[j].w);
            const float2 ld = loc[(size_t)b * NPRI + p];
            ll += sl1(ld.x - lt0) + sl1(ld.y - lt1);
            lr += sl1(reg[(size_t)b * NPRI + p] - ts[5]);
            ++np;
        }
    }
    #pragma unroll
    for (int s = 32; s > 0; s >>= 1) {
        ll += __shfl_down(ll, s, 64);
        lr += __shfl_down(lr, s, 64);
        np += __shfl_down(np, s, 64);
    }
    __shared__ float sred[4][2];
    __shared__ int sredn[4];
    const int lane = tid & 63, w = tid >> 6;
    if (lane == 0) { sred[w][0] = ll; sred[w][1] = lr; sredn[w] = np; }
    __syncthreads();
    if (tid == 0) {
        const float tl = sred[0][0] + sred[1][0] + sred[2][0] + sred[3][0];
        const float tr = sred[0][1] + sred[1][1] + sred[2][1] + sred[3][1];
        const int tn = sredn[0] + sredn[1] + sredn[2] + sredn[3];
        if (tn) {
            atomicAdd(&acc[0], (double)tl);
            atomicAdd(&acc[2], (double)tr);
            atomicAdd(&npos[b], tn);
        }
    }
}

// ---- wave-aggregated LDS histogram add (handles hot bins without serialization)
__device__ __forceinline__ void waveAgg(unsigned int* h, unsigned bin, int lane) {
    unsigned long long todo = __ballot(1);
    while (todo) {
        const int leader = __builtin_ctzll(todo);
        const unsigned lb = (unsigned)__shfl((int)bin, leader, 64);
        const unsigned long long m = __ballot(bin == lb);
        if (lane == leader) atomicAdd(&h[lb], (unsigned)__popcll(m));
        todo &= ~m;
    }
}

// ------- kSelBCE: radix select + tie cutoff + BCE + finalize, 1 block/batch -------
__global__ __launch_bounds__(1024) void kSelBCE(const float* __restrict__ lcpp,
                                                const unsigned char* __restrict__ confb,
                                                const float4* __restrict__ cnf,
                                                const int* __restrict__ npos,
                                                double* __restrict__ acc,
                                                int* __restrict__ done,
                                                float* __restrict__ out) {
    const int b = blockIdx.x, tid = threadIdx.x, lane = tid & 63, w = tid >> 6;
    __shared__ unsigned int h[256], scan[256];
    __shared__ int res[2];
    __shared__ int wsum[16];
    __shared__ int srun;
    __shared__ int sIstar;
    __shared__ float sc[16];
    const float4* v4 = (const float4*)(lcpp + (size_t)b * NPRI);

    int k = min(3 * npos[b], NPRI - 1);
    if (k < 1) k = 1;
    int r = k - 1;
    unsigned P = 0, eq = 0;

    for (int pass = 0; pass < 4; ++pass) {
        if (tid < 256) h[tid] = 0;
        __syncthreads();
        const int shift = 24 - 8 * pass;
        for (int it = 0; it < NPRI / 4 / 1024; ++it) {     // 8 float4 per thread
            const float4 xx = v4[it * 1024 + tid];
            const unsigned u0 = __float_as_uint(xx.x), u1 = __float_as_uint(xx.y);
            const unsigned u2 = __float_as_uint(xx.z), u3 = __float_as_uint(xx.w);
            if (pass == 0) {
                waveAgg(h, u0 >> 24, lane);
                waveAgg(h, u1 >> 24, lane);
                waveAgg(h, u2 >> 24, lane);
                waveAgg(h, u3 >> 24, lane);
            } else {
                const int hs = shift + 8;
                if ((u0 >> hs) == P) atomicAdd(&h[(u0 >> shift) & 255u], 1u);
                if ((u1 >> hs) == P) atomicAdd(&h[(u1 >> shift) & 255u], 1u);
                if ((u2 >> hs) == P) atomicAdd(&h[(u2 >> shift) & 255u], 1u);
                if ((u3 >> hs) == P) atomicAdd(&h[(u3 >> shift) & 255u], 1u);
            }
        }
        __syncthreads();
        if (tid < 256) scan[tid] = h[tid];
        __syncthreads();
        #pragma unroll
        for (int off = 1; off < 256; off <<= 1) {
            unsigned add = 0;
            if (tid < 256 && tid + off < 256) add = scan[tid + off];
            __syncthreads();
            if (tid < 256) scan[tid] += add;
            __syncthreads();
        }
        if (tid < 256) {
            const int sfx = (int)scan[tid];
            const int nxt = (tid < 255) ? (int)scan[tid + 1] : 0;
            if (sfx >= r + 1 && nxt < r + 1) { res[0] = tid; res[1] = r - nxt; }
        }
        __syncthreads();
        const int bsel = res[0];
        r = res[1];
        if (pass == 3) eq = h[bsel];
        P = (P << 8) | (unsigned)bsel;
        __syncthreads();
    }
    const unsigned T = P;
    const int rem = r + 1;
    int Istar = 0x7FFFFFFF;                               // all ties selected
    if ((int)eq > rem) {                                  // rare: excess ties, stable cutoff
        if (tid == 0) { srun = 0; sIstar = 0x7FFFFFFF; }
        __syncthreads();
        const float* v = (const float*)v4;
        for (int chunk = 0; chunk < NPRI / 1024; ++chunk) {
            const int i = chunk * 1024 + tid;
            const bool tie = (__float_as_uint(v[i]) == T);
            const unsigned long long msk = __ballot(tie);
            if (lane == 0) wsum[w] = __popcll(msk);
            __syncthreads();
            int pre = 0, tot = 0;
            #pragma unroll
            for (int q = 0; q < 16; ++q) { const int c = wsum[q]; if (q < w) pre += c; tot += c; }
            const int myrank = srun + pre + __popcll(msk & ((1ull << lane) - 1ull));
            if (tie && myrank == rem - 1) sIstar = i;     // index of last accepted tie
            __syncthreads();
            if (tid == 0) srun += tot;
            __syncthreads();
            if (srun >= rem) break;                       // uniform
        }
        __syncthreads();
        Istar = sIstar;
    }

    // ---- BCE over selected (lcpp L2-hot from the radix passes) ----
    const float* v = (const float*)v4;
    const unsigned char* cb = confb + (size_t)b * NPRI;
    float local = 0.0f;
    for (int it = 0; it < NPRI / 1024; ++it) {
        const int i = it * 1024 + tid;
        const unsigned int u = __float_as_uint(v[i]);
        const int c = cb[i];
        if (c > 0 || u > T || (u == T && i <= Istar)) {
            const float4 xx = cnf[(size_t)b * NPRI + i];
            local += bce1(xx.x, c == 0) + bce1(xx.y, c == 1) + bce1(xx.z, c == 2) + bce1(xx.w, c == 3);
        }
    }
    #pragma unroll
    for (int s = 32; s > 0; s >>= 1) local += __shfl_down(local, s, 64);
    if (lane == 0) sc[w] = local;
    __syncthreads();
    __shared__ bool slast;
    if (tid == 0) {
        float t = 0.0f;
        #pragma unroll
        for (int q = 0; q < 16; ++q) t += sc[q];
        atomicAdd(&acc[1], (double)t);
        __threadfence();
        const int old = atomicAdd(done, 1);
        slast = (old == BATCH - 1);
    }
    __syncthreads();
    if (slast && tid == 0) {
        __threadfence();
        int n = 0;
        for (int q = 0; q < BATCH; ++q) n += npos[q];
        const double a0 = atomicAdd(&acc[0], 0.0);        // atomic-RMW read: cross-XCD safe
        const double a1 = atomicAdd(&acc[1], 0.0);
        const double a2 = atomicAdd(&acc[2], 0.0);
        const double N = (double)n;
        out[0] = (float)(a0 / N);
        out[1] = (float)(a1 / N);
        out[2] = (float)(a2 / N);
    }
}

extern "C" void kernel_launch(void* const* d_in, const int* in_sizes, int n_in,
                              void* d_out, int out_size, void* d_ws, size_t ws_size,
                              hipStream_t stream) {
    const float* loc = (const float*)d_in[0];
    const float* cnfp = (const float*)d_in[1];
    const float* regp = (const float*)d_in[2];
    const float* tgt = (const float*)d_in[3];
    const float* pri = (const float*)d_in[4];

    char* ws = (char*)d_ws;
    double* acc = (double*)(ws + OFF_ACC);
    int* done = (int*)(ws + OFF_DONE);
    int* npos = (int*)(ws + OFF_NPOS);
    unsigned long long* bpk = (unsigned long long*)(ws + OFF_BPK);
    float* lcpp = (float*)(ws + OFF_LCPP);
    unsigned char* confb = (unsigned char*)(ws + OFF_CONF);

    hipMemsetAsync(ws, 0, HDR_BYTES, stream);   // acc/done/npos/bpk header

    kA<<<dim3(8, BATCH), 256, 0, stream>>>(tgt, (const float4*)pri, bpk);
    kB<<<dim3(NPRI / 1024, BATCH), 256, 0, stream>>>(tgt, (const float4*)pri, (const float2*)loc,
                                                     (const float4*)cnfp, regp, bpk, lcpp, confb,
                                                     acc, npos);
    kSelBCE<<<BATCH, 1024, 0, stream>>>(lcpp, confb, (const float4*)cnfp, npos, acc,
                                        done, (float*)d_out);
}

// Round 6
// 404.839 us; speedup vs baseline: 2.1947x; 1.0227x over previous
//
#include <hip/hip_runtime.h>
#include <math.h>

#define BATCH 128
#define NPRI  32768
#define NOBJ  20
#define THRSH 0.5f
#define VARNC 0.1f

// ---- workspace layout (~37 MB) ----
#define OFF_ACC   0                      // 3 doubles
#define OFF_DONE  48                     // int
#define OFF_NPOS  64                     // 128 ints
#define OFF_BPK   1024                   // 2560 ull -> ends 21504
#define OFF_HIST  32768                  // 128*1024 uint = 512 KB (zeroed by kA)
#define OFF_MATCH (1 << 20)              // 16 MB u32: (iou_bits & ~31) | best_truth_idx
#define OFF_LCPP  (17 << 20)             // 16 MB float
#define OFF_CONF  (33 << 20)             // 4 MB bytes
#define HDR_BYTES 21504

__device__ __forceinline__ float sl1(float d) {
    d = fabsf(d);
    return (d < 1.0f) ? 0.5f * d * d : d - 0.5f;
}
__device__ __forceinline__ float bce1(float x, bool hot) {
    float tgt = hot ? 0.925f : 0.025f;
    return fmaxf(x, 0.0f) - x * tgt + log1pf(expf(-fabsf(x)));
}

// ---- kA: one IoU sweep serving BOTH argmaxes; zeroes hist; stores per-prior match ----
__global__ __launch_bounds__(256) void kA(const float* __restrict__ targets,
                                          const float4* __restrict__ priors,
                                          unsigned long long* __restrict__ bpk,
                                          unsigned* __restrict__ match,
                                          unsigned* __restrict__ hist) {
    const int b = blockIdx.y, tid = threadIdx.x;
    if (tid < 128) hist[b * 1024 + blockIdx.x * 128 + tid] = 0;   // re-zero every launch
    const int base = blockIdx.x * 4096;

    float px0[16], py0[16], px1[16], py1[16], ab[16];
    #pragma unroll
    for (int it = 0; it < 16; ++it) {
        const float4 pr = priors[base + it * 256 + tid];
        px0[it] = pr.x - pr.z * 0.5f; py0[it] = pr.y - pr.w * 0.5f;
        px1[it] = pr.x + pr.z * 0.5f; py1[it] = pr.y + pr.w * 0.5f;
        ab[it] = (px1[it] - px0[it]) * (py1[it] - py0[it]);
    }
    float ppi[16], ppd[16]; int ppt[16];
    #pragma unroll
    for (int it = 0; it < 16; ++it) { ppi[it] = -1.0f; ppd[it] = 1.0f; ppt[it] = 0; }

    __shared__ unsigned long long skey[NOBJ];
    if (tid < NOBJ) skey[tid] = 0ull;
    __syncthreads();
    const int lane = tid & 63;
    const float* tb = targets + b * NOBJ * 6;

    #pragma unroll 1
    for (int o = 0; o < NOBJ; ++o) {
        const float t0 = tb[o * 6], t1 = tb[o * 6 + 1], t2 = tb[o * 6 + 2], t3 = tb[o * 6 + 3];
        const float aa = (t2 - t0) * (t3 - t1);
        float bi = -1.0f, bd = 1.0f; int bp = 0;
        #pragma unroll
        for (int it = 0; it < 16; ++it) {
            float ix = fminf(t2, px1[it]) - fmaxf(t0, px0[it]); ix = fmaxf(ix, 0.0f);
            float iy = fminf(t3, py1[it]) - fmaxf(t1, py0[it]); iy = fmaxf(iy, 0.0f);
            const float inter = ix * iy;
            const float den = aa + ab[it] - inter;
            // per-prior argmax over truths (min-o on ties: strict >, o ascending)
            if (inter * ppd[it] > ppi[it] * den) { ppi[it] = inter; ppd[it] = den; ppt[it] = o; }
            // per-truth argmax over priors (min-p on ties: strict >, p ascending)
            if (inter * bd > bi * den) { bi = inter; bd = den; bp = base + it * 256 + tid; }
        }
        const float iou = bi / bd;
        unsigned long long key = ((unsigned long long)__float_as_uint(iou) << 32)
                               | (unsigned long long)(0xFFFFFFFFu - (unsigned)bp);
        #pragma unroll
        for (int s = 32; s > 0; s >>= 1) {
            unsigned long long k2 = __shfl_xor(key, s, 64);
            if (k2 > key) key = k2;
        }
        if (lane == 0) atomicMax(&skey[o], key);
    }
    #pragma unroll
    for (int it = 0; it < 16; ++it) {
        const float iou = ppi[it] / ppd[it];              // same div order as reference
        match[(size_t)b * NPRI + base + it * 256 + tid] =
            (__float_as_uint(iou) & 0xFFFFFFE0u) | (unsigned)ppt[it];
    }
    __syncthreads();
    if (tid < NOBJ) atomicMax(&bpk[b * NOBJ + tid], skey[tid]);
}

// ---- kB: read match, override, lse/losses, lcpp/confb, level-0 hist ----
__global__ __launch_bounds__(256) void kB(const float* __restrict__ targets,
                                          const float4* __restrict__ priors,
                                          const float2* __restrict__ loc,
                                          const float4* __restrict__ cnf,
                                          const float* __restrict__ reg,
                                          const unsigned long long* __restrict__ bpk,
                                          const unsigned* __restrict__ match,
                                          float* __restrict__ lcpp,
                                          unsigned char* __restrict__ confb,
                                          unsigned* __restrict__ hist,
                                          double* __restrict__ acc,
                                          int* __restrict__ npos) {
    const int b = blockIdx.y, tid = threadIdx.x;
    const int base = blockIdx.x * 1024;
    const float* tb = targets + b * NOBJ * 6;            // block-uniform -> s_loads
    const unsigned long long* bb = bpk + b * NOBJ;
    __shared__ unsigned lh[1024];
    lh[tid] = 0; lh[tid + 256] = 0; lh[tid + 512] = 0; lh[tid + 768] = 0;

    unsigned mu[4]; float4 x[4];
    #pragma unroll
    for (int j = 0; j < 4; ++j) mu[j] = match[(size_t)b * NPRI + base + j * 256 + tid];
    #pragma unroll
    for (int j = 0; j < 4; ++j) x[j] = cnf[(size_t)b * NPRI + base + j * 256 + tid];

    float bto[4]; int bt[4];
    #pragma unroll
    for (int j = 0; j < 4; ++j) {
        bto[j] = __uint_as_float(mu[j] & 0xFFFFFFE0u);
        bt[j] = (int)(mu[j] & 31u);
    }
    #pragma unroll
    for (int o = 0; o < NOBJ; ++o) {                     // serial scatter override, last o wins
        const int bpi = (int)(0xFFFFFFFFu - (unsigned)(bb[o] & 0xFFFFFFFFull));
        #pragma unroll
        for (int j = 0; j < 4; ++j)
            if (bpi == base + j * 256 + tid) { bto[j] = 2.0f; bt[j] = o; }
    }
    __syncthreads();                                      // lh zero visible before atomics

    float ll = 0.0f, lr = 0.0f; int np = 0;
    #pragma unroll
    for (int j = 0; j < 4; ++j) {
        const int p = base + j * 256 + tid;
        const float* ts = tb + bt[j] * 6;
        int c = 0;
        if (bto[j] >= THRSH) c = (int)ts[4];
        const float m = fmaxf(fmaxf(x[j].x, x[j].y), fmaxf(x[j].z, x[j].w));
        const float lse = m + logf(expf(x[j].x - m) + expf(x[j].y - m) +
                                   expf(x[j].z - m) + expf(x[j].w - m));
        const float picked = (c == 0) ? x[j].x : (c == 1) ? x[j].y : (c == 2) ? x[j].z : x[j].w;
        const float lval = (c > 0) ? 0.0f : (lse - picked);
        lcpp[(size_t)b * NPRI + p] = lval;
        confb[(size_t)b * NPRI + p] = (unsigned char)c;
        atomicAdd(&lh[__float_as_uint(lval) >> 21], 1u);  // sign=0 -> bin < 1024
        if (c > 0) {
            const float4 pr = priors[p];
            const float cx = (ts[0] + ts[2]) * 0.5f, cy = (ts[1] + ts[3]) * 0.5f;
            const float lt0 = (cx - pr.x) / (VARNC * pr.z);
            const float lt1 = (cy - pr.y) / (VARNC * pr.w);
            const float2 ld = loc[(size_t)b * NPRI + p];
            ll += sl1(ld.x - lt0) + sl1(ld.y - lt1);
            lr += sl1(reg[(size_t)b * NPRI + p] - ts[5]);
            ++np;
        }
    }
    #pragma unroll
    for (int s = 32; s > 0; s >>= 1) {
        ll += __shfl_down(ll, s, 64);
        lr += __shfl_down(lr, s, 64);
        np += __shfl_down(np, s, 64);
    }
    __shared__ float sred[4][2];
    __shared__ int sredn[4];
    const int lane = tid & 63, w = tid >> 6;
    if (lane == 0) { sred[w][0] = ll; sred[w][1] = lr; sredn[w] = np; }
    __syncthreads();                                      // covers lh atomics + sred
    #pragma unroll
    for (int q = 0; q < 4; ++q) {                         // flush sparse hist (few nonzero bins)
        const unsigned v = lh[tid + q * 256];
        if (v) atomicAdd(&hist[b * 1024 + tid + q * 256], v);
    }
    if (tid == 0) {
        const float tl = sred[0][0] + sred[1][0] + sred[2][0] + sred[3][0];
        const float tr = sred[0][1] + sred[1][1] + sred[2][1] + sred[3][1];
        const int tn = sredn[0] + sredn[1] + sredn[2] + sredn[3];
        if (tn) {
            atomicAdd(&acc[0], (double)tl);
            atomicAdd(&acc[2], (double)tr);
            atomicAdd(&npos[b], tn);
        }
    }
}

// ------- kSelBCE: hist-fed radix select (2 data passes) + tie + BCE + finalize -------
__global__ __launch_bounds__(1024) void kSelBCE(const float* __restrict__ lcpp,
                                                const unsigned char* __restrict__ confb,
                                                const float4* __restrict__ cnf,
                                                const unsigned* __restrict__ hist,
                                                const int* __restrict__ npos,
                                                double* __restrict__ acc,
                                                int* __restrict__ done,
                                                float* __restrict__ out) {
    const int b = blockIdx.x, tid = threadIdx.x, lane = tid & 63, w = tid >> 6;
    __shared__ unsigned h[2048];
    __shared__ unsigned wtot[16];
    __shared__ int res[2];
    __shared__ int wsum[16];
    __shared__ int srun, sIstar;
    __shared__ float sc[16];
    const float4* v4 = (const float4*)(lcpp + (size_t)b * NPRI);
    const float* v = (const float*)v4;

    int k = min(3 * npos[b], NPRI - 1);
    if (k < 1) k = 1;
    int r = k - 1;

    // ---- pass 0: scan precomputed 1024-bin hist (no data read) ----
    {
        const unsigned a = hist[b * 1024 + tid];
        unsigned s = a;
        #pragma unroll
        for (int d = 1; d < 64; d <<= 1) { const unsigned t = __shfl_down(s, d, 64); if (lane + d < 64) s += t; }
        if (lane == 0) wtot[w] = s;
        __syncthreads();
        unsigned add = 0;
        #pragma unroll
        for (int q = 0; q < 16; ++q) if (q > w) add += wtot[q];
        const unsigned Sincl = s + add;                   // suffix over bins >= tid
        if (Sincl >= (unsigned)(r + 1) && Sincl - a < (unsigned)(r + 1)) { res[0] = tid; res[1] = r - (int)(Sincl - a); }
        __syncthreads();
    }
    const unsigned B1 = (unsigned)res[0];                 // top 11 bits
    r = res[1];
    __syncthreads();

    // ---- pass 1: 2048-bin hist of bits[20:10] among B1 candidates ----
    h[tid] = 0; h[tid + 1024] = 0;
    __syncthreads();
    for (int it = 0; it < NPRI / 4 / 1024; ++it) {
        const float4 xx = v4[it * 1024 + tid];
        const unsigned u0 = __float_as_uint(xx.x), u1 = __float_as_uint(xx.y);
        const unsigned u2 = __float_as_uint(xx.z), u3 = __float_as_uint(xx.w);
        if ((u0 >> 21) == B1) atomicAdd(&h[(u0 >> 10) & 2047u], 1u);
        if ((u1 >> 21) == B1) atomicAdd(&h[(u1 >> 10) & 2047u], 1u);
        if ((u2 >> 21) == B1) atomicAdd(&h[(u2 >> 10) & 2047u], 1u);
        if ((u3 >> 21) == B1) atomicAdd(&h[(u3 >> 10) & 2047u], 1u);
    }
    __syncthreads();
    {
        const unsigned a = h[2 * tid], b2 = h[2 * tid + 1];
        const unsigned sv = a + b2;
        unsigned s = sv;
        #pragma unroll
        for (int d = 1; d < 64; d <<= 1) { const unsigned t = __shfl_down(s, d, 64); if (lane + d < 64) s += t; }
        if (lane == 0) wtot[w] = s;
        __syncthreads();
        unsigned add = 0;
        #pragma unroll
        for (int q = 0; q < 16; ++q) if (q > w) add += wtot[q];
        const unsigned Sincl = s + add;
        const unsigned r1 = (unsigned)(r + 1);
        if (Sincl >= r1 && Sincl - a < r1) { res[0] = 2 * tid; res[1] = r - (int)(Sincl - a); }
        if (Sincl - a >= r1 && Sincl - sv < r1) { res[0] = 2 * tid + 1; res[1] = r - (int)(Sincl - sv); }
        __syncthreads();
    }
    const unsigned P22 = (B1 << 11) | (unsigned)res[0];   // top 22 bits
    r = res[1];
    __syncthreads();

    // ---- pass 2: 1024-bin hist of bits[9:0] among P22 candidates ----
    h[tid] = 0;
    __syncthreads();
    for (int it = 0; it < NPRI / 4 / 1024; ++it) {
        const float4 xx = v4[it * 1024 + tid];
        const unsigned u0 = __float_as_uint(xx.x), u1 = __float_as_uint(xx.y);
        const unsigned u2 = __float_as_uint(xx.z), u3 = __float_as_uint(xx.w);
        if ((u0 >> 10) == P22) atomicAdd(&h[u0 & 1023u], 1u);
        if ((u1 >> 10) == P22) atomicAdd(&h[u1 & 1023u], 1u);
        if ((u2 >> 10) == P22) atomicAdd(&h[u2 & 1023u], 1u);
        if ((u3 >> 10) == P22) atomicAdd(&h[u3 & 1023u], 1u);
    }
    __syncthreads();
    {
        const unsigned a = h[tid];
        unsigned s = a;
        #pragma unroll
        for (int d = 1; d < 64; d <<= 1) { const unsigned t = __shfl_down(s, d, 64); if (lane + d < 64) s += t; }
        if (lane == 0) wtot[w] = s;
        __syncthreads();
        unsigned add = 0;
        #pragma unroll
        for (int q = 0; q < 16; ++q) if (q > w) add += wtot[q];
        const unsigned Sincl = s + add;
        if (Sincl >= (unsigned)(r + 1) && Sincl - a < (unsigned)(r + 1)) { res[0] = tid; res[1] = r - (int)(Sincl - a); }
        __syncthreads();
    }
    const unsigned T = (P22 << 10) | (unsigned)res[0];    // exact k-th value
    r = res[1];
    const int eq = (int)h[res[0]];
    const int rem = r + 1;                                 // ties to accept (stable, low index first)
    __syncthreads();

    // ---- rare: excess ties -> stable cutoff index ----
    int Istar = 0x7FFFFFFF;
    if (eq > rem) {
        if (tid == 0) { srun = 0; sIstar = 0x7FFFFFFF; }
        __syncthreads();
        for (int chunk = 0; chunk < NPRI / 1024; ++chunk) {
            const int i = chunk * 1024 + tid;
            const bool tie = (__float_as_uint(v[i]) == T);
            const unsigned long long msk = __ballot(tie);
            if (lane == 0) wsum[w] = __popcll(msk);
            __syncthreads();
            int pre = 0, tot = 0;
            #pragma unroll
            for (int q = 0; q < 16; ++q) { const int c = wsum[q]; if (q < w) pre += c; tot += c; }
            const int myrank = srun + pre + __popcll(msk & ((1ull << lane) - 1ull));
            if (tie && myrank == rem - 1) sIstar = i;
            __syncthreads();
            if (tid == 0) srun += tot;
            __syncthreads();
            if (srun >= rem) break;                        // uniform
        }
        __syncthreads();
        Istar = sIstar;
    }

    // ---- BCE over selected ----
    const unsigned char* cb = confb + (size_t)b * NPRI;
    float local = 0.0f;
    for (int it = 0; it < NPRI / 1024; ++it) {
        const int i = it * 1024 + tid;
        const unsigned int u = __float_as_uint(v[i]);
        const int c = cb[i];
        if (c > 0 || u > T || (u == T && i <= Istar)) {
            const float4 xx = cnf[(size_t)b * NPRI + i];
            local += bce1(xx.x, c == 0) + bce1(xx.y, c == 1) + bce1(xx.z, c == 2) + bce1(xx.w, c == 3);
        }
    }
    #pragma unroll
    for (int s = 32; s > 0; s >>= 1) local += __shfl_down(local, s, 64);
    if (lane == 0) sc[w] = local;
    __syncthreads();
    __shared__ bool slast;
    if (tid == 0) {
        float t = 0.0f;
        #pragma unroll
        for (int q = 0; q < 16; ++q) t += sc[q];
        atomicAdd(&acc[1], (double)t);
        __threadfence();
        const int old = atomicAdd(done, 1);
        slast = (old == BATCH - 1);
    }
    __syncthreads();
    if (slast && tid == 0) {
        __threadfence();
        int n = 0;
        for (int q = 0; q < BATCH; ++q) n += npos[q];
        const double a0 = atomicAdd(&acc[0], 0.0);         // atomic-RMW read: cross-XCD safe
        const double a1 = atomicAdd(&acc[1], 0.0);
        const double a2 = atomicAdd(&acc[2], 0.0);
        const double N = (double)n;
        out[0] = (float)(a0 / N);
        out[1] = (float)(a1 / N);
        out[2] = (float)(a2 / N);
    }
}

extern "C" void kernel_launch(void* const* d_in, const int* in_sizes, int n_in,
                              void* d_out, int out_size, void* d_ws, size_t ws_size,
                              hipStream_t stream) {
    const float* loc = (const float*)d_in[0];
    const float* cnfp = (const float*)d_in[1];
    const float* regp = (const float*)d_in[2];
    const float* tgt = (const float*)d_in[3];
    const float* pri = (const float*)d_in[4];

    char* ws = (char*)d_ws;
    double* acc = (double*)(ws + OFF_ACC);
    int* done = (int*)(ws + OFF_DONE);
    int* npos = (int*)(ws + OFF_NPOS);
    unsigned long long* bpk = (unsigned long long*)(ws + OFF_BPK);
    unsigned* hist = (unsigned*)(ws + OFF_HIST);
    unsigned* match = (unsigned*)(ws + OFF_MATCH);
    float* lcpp = (float*)(ws + OFF_LCPP);
    unsigned char* confb = (unsigned char*)(ws + OFF_CONF);

    hipMemsetAsync(ws, 0, HDR_BYTES, stream);   // acc/done/npos/bpk (hist zeroed by kA)

    kA<<<dim3(8, BATCH), 256, 0, stream>>>(tgt, (const float4*)pri, bpk, match, hist);
    kB<<<dim3(NPRI / 1024, BATCH), 256, 0, stream>>>(tgt, (const float4*)pri, (const float2*)loc,
                                                     (const float4*)cnfp, regp, bpk, match,
                                                     lcpp, confb, hist, acc, npos);
    kSelBCE<<<BATCH, 1024, 0, stream>>>(lcpp, confb, (const float4*)cnfp, hist, npos, acc,
                                        done, (float*)d_out);
}